// Round 4
// baseline (243.773 us; speedup 1.0000x reference)
//
#include <hip/hip_runtime.h>
#include <math.h>

#define BATCH 128
#define DIM   8192
#define HW    49
#define PAIRS 2401            // 49*49
#define SLOT  2512            // per-partial slot: 2401 G + 49 nA + 49 nB + pad

// ws float offsets
#define WS_MSE    0
#define WS_VARA   1
#define WS_VARB   2
#define WS_DIAGA  3
#define WS_DIAGB  4
#define WS_S1     5
#define WS_S2     6
#define WS_S3     7
#define WS_S4     8
#define WS_SK2A   9
#define WS_SK2B   10
#define COLS_OFF    16                         // sa,qa,sb,qb: 4*DIM
#define GRAMA_OFF   32784
#define GRAMB_OFF   49168
#define GK2PART_OFF 65552                      // 128 blocks * 16384
#define L1PART_BIG  2162704                    // 1024 blocks * SLOT
#define WS_NEED_FLOATS (L1PART_BIG + 1024 * SLOT)   // ~19 MB
#define L1PART_SMALL 65552                     // fallback: 128 batch slots (atomic)

typedef __attribute__((ext_vector_type(8))) short bf16x8;
typedef __attribute__((ext_vector_type(4))) float f32x4;

union BF8U { unsigned u[4]; bf16x8 v; };

__device__ __forceinline__ unsigned cvtpk(float lo, float hi) {
    unsigned r;
    asm("v_cvt_pk_bf16_f32 %0, %1, %2" : "=v"(r) : "v"(lo), "v"(hi));
    return r;
}
__device__ __forceinline__ float sq4(float4 v) {
    return v.x * v.x + v.y * v.y + v.z * v.z + v.w * v.w;
}

// ---------------------------------------------------------------------------
// L1: per-batch padded 64x64 Gram of 49x8192 features, bf16 MFMA, NO LDS
// staging, NO main-loop barriers. grid = 128 batches * 8 K-splits, 256 thr.
// Each wave owns K-chunk 256 (8 steps of K=32), loads A/B fragments DIRECTLY
// from global (frag layout: row=lane&15, k=(lane>>4)*8+e — HW-verified), cvt
// fp32->bf16 in-register (v_cvt_pk_bf16_f32), 16 MFMA per step into a full
// 64x64 accumulator. Rows>=49 clamp to row 48 (garbage lands in discarded
// C rows/cols). Epilogue: LDS ds_add_f32 reduction across the 4 waves, one
// coalesced store per block to its partial slot (RED) / atomics (fallback).
// ---------------------------------------------------------------------------
template<bool RED>
__global__ __launch_bounds__(256) void l1_gram(const float* __restrict__ za,
                                               const float* __restrict__ zb,
                                               float* __restrict__ l1part)
{
    __shared__ float red[64 * 64 + 128];

    const int tid = threadIdx.x;
    const int batch = blockIdx.x >> 3;
    const int ks    = blockIdx.x & 7;
    const int lane = tid & 63;
    const int wv   = tid >> 6;
    const int r = lane & 15;          // fragment row / C col
    const int g = lane >> 4;          // k-group / C row-quad

    const float* Ab = za + (size_t)batch * HW * DIM;
    const float* Bb = zb + (size_t)batch * HW * DIM;
    const int kb = ks * 1024 + wv * 256 + g * 8;

    const float* pA[4];
    const float* pB[4];
#pragma unroll
    for (int m = 0; m < 4; ++m) {
        int rowm = 16 * m + r; if (rowm > 48) rowm = 48;
        pA[m] = Ab + (size_t)rowm * DIM + kb;
        pB[m] = Bb + (size_t)rowm * DIM + kb;
    }

    f32x4 acc[4][4];
#pragma unroll
    for (int m = 0; m < 4; ++m)
#pragma unroll
        for (int n = 0; n < 4; ++n) acc[m][n] = (f32x4){0.f, 0.f, 0.f, 0.f};
    float na[4] = {0.f, 0.f, 0.f, 0.f}, nb[4] = {0.f, 0.f, 0.f, 0.f};

    float4 XA[4][2], XB[4][2];
    bf16x8 FA[4], FB[4];

#define L1_LOADX(t) do {                                                      \
    _Pragma("unroll") for (int m = 0; m < 4; ++m) {                           \
        XA[m][0] = *(const float4*)(pA[m] + (t) * 32);                        \
        XA[m][1] = *(const float4*)(pA[m] + (t) * 32 + 4);                    \
        XB[m][0] = *(const float4*)(pB[m] + (t) * 32);                        \
        XB[m][1] = *(const float4*)(pB[m] + (t) * 32 + 4);                    \
    } } while (0)

    L1_LOADX(0);
#pragma unroll
    for (int t = 0; t < 8; ++t) {
        // convert current step to bf16 frags + accumulate norms (frees XA/XB)
#pragma unroll
        for (int m = 0; m < 4; ++m) {
            BF8U fa, fb;
            fa.u[0] = cvtpk(XA[m][0].x, XA[m][0].y);
            fa.u[1] = cvtpk(XA[m][0].z, XA[m][0].w);
            fa.u[2] = cvtpk(XA[m][1].x, XA[m][1].y);
            fa.u[3] = cvtpk(XA[m][1].z, XA[m][1].w);
            fb.u[0] = cvtpk(XB[m][0].x, XB[m][0].y);
            fb.u[1] = cvtpk(XB[m][0].z, XB[m][0].w);
            fb.u[2] = cvtpk(XB[m][1].x, XB[m][1].y);
            fb.u[3] = cvtpk(XB[m][1].z, XB[m][1].w);
            FA[m] = fa.v; FB[m] = fb.v;
            if (16 * m + r < HW) {
                na[m] += sq4(XA[m][0]) + sq4(XA[m][1]);
                nb[m] += sq4(XB[m][0]) + sq4(XB[m][1]);
            }
        }
        if (t < 7) L1_LOADX(t + 1);          // issue next step's 16 loads
        __builtin_amdgcn_sched_barrier(0);   // keep loads above the MFMA cluster
#pragma unroll
        for (int m = 0; m < 4; ++m)
#pragma unroll
            for (int n = 0; n < 4; ++n)
                acc[m][n] = __builtin_amdgcn_mfma_f32_16x16x32_bf16(FA[m], FB[n], acc[m][n], 0, 0, 0);
    }
#undef L1_LOADX

    // ---- block epilogue: reduce 4 waves via LDS ----
    for (int i = tid; i < 64 * 64 + 128; i += 256) red[i] = 0.f;
    __syncthreads();

#pragma unroll
    for (int m = 0; m < 4; ++m)
#pragma unroll
        for (int n = 0; n < 4; ++n)
#pragma unroll
            for (int rr = 0; rr < 4; ++rr)
                atomicAdd(&red[(16 * m + g * 4 + rr) * 64 + 16 * n + r], acc[m][n][rr]);

#pragma unroll
    for (int m = 0; m < 4; ++m) {
        float vA = na[m], vB = nb[m];
        vA += __shfl_xor(vA, 16);  vB += __shfl_xor(vB, 16);
        vA += __shfl_xor(vA, 32);  vB += __shfl_xor(vB, 32);
        if (g == 0 && 16 * m + r < HW) {
            atomicAdd(&red[4096 + 16 * m + r], vA);
            atomicAdd(&red[4096 + 64 + 16 * m + r], vB);
        }
    }
    __syncthreads();

    float* gout = l1part + (size_t)(RED ? blockIdx.x : batch) * SLOT;
    for (int e = tid; e < PAIRS; e += 256) {
        int row = e / 49, col = e - row * 49;
        float v = red[row * 64 + col];
        if (RED) gout[e] = v; else atomicAdd(&gout[e], v);
    }
    if (tid < HW) {
        float v = red[4096 + tid];
        if (RED) gout[PAIRS + tid] = v; else atomicAdd(&gout[PAIRS + tid], v);
    } else if (tid >= 64 && tid < 64 + HW) {
        float v = red[4096 + 64 + (tid - 64)];
        if (RED) gout[PAIRS + HW + (tid - 64)] = v;
        else atomicAdd(&gout[PAIRS + HW + (tid - 64)], v);
    }
}

// ---------------------------------------------------------------------------
// L2: per-batch matching. RED mode folds the 8-way K-split reduction of the
// l1 partial Grams/norms into the d2f build. Selection logic unchanged.
// ---------------------------------------------------------------------------
template<bool RED>
__global__ __launch_bounds__(256) void l2_match(const float* __restrict__ ga,
                                                const float* __restrict__ gb,
                                                float* __restrict__ ws,
                                                const float* __restrict__ l1part)
{
    __shared__ float d2f[PAIRS];
    __shared__ float d2g[PAIRS];
    __shared__ float nAs[49], nBs[49];
    __shared__ float gax[49], gay[49], gbx[49], gby[49];
    __shared__ float mval[4][49];
    __shared__ int   midx[4][49];

    const int tid = threadIdx.x;
    const int batch = blockIdx.x;
    const float* P0 = l1part + (size_t)batch * (RED ? (8 * SLOT) : SLOT);

    auto rd = [&](int off) -> float {
        if (!RED) return P0[off];
        float s = 0.f;
#pragma unroll
        for (int ss = 0; ss < 8; ++ss) s += P0[ss * SLOT + off];
        return s;
    };

    if (tid < 49) nAs[tid] = rd(PAIRS + tid);
    else if (tid >= 64 && tid < 113) nBs[tid - 64] = rd(PAIRS + 49 + (tid - 64));
    if (tid >= 128 && tid < 177) {
        int i = tid - 128;
        gax[i] = ga[batch * 98 + i * 2];
        gay[i] = ga[batch * 98 + i * 2 + 1];
    } else if (tid >= 192 && tid < 241) {
        int i = tid - 192;
        gbx[i] = gb[batch * 98 + i * 2];
        gby[i] = gb[batch * 98 + i * 2 + 1];
    }
    __syncthreads();
    for (int e = tid; e < PAIRS; e += 256) {
        int i = e / 49, j = e - i * 49;
        d2f[e] = nAs[i] + nBs[j] - 2.0f * rd(e);
        float dx = gax[i] - gbx[j], dy = gay[i] - gby[j];
        d2g[e] = dx * dx + dy * dy;
    }
    __syncthreads();
    const int task = tid >> 6, l = tid & 63;
    if (l < 49) {
        float bv = 3.0e38f; int bi = 0;
        if (task == 0) {
            for (int j = 0; j < 49; ++j) { float v = d2f[l * 49 + j]; if (v < bv) { bv = v; bi = j; } }
        } else if (task == 1) {
            for (int i = 0; i < 49; ++i) { float v = d2f[i * 49 + l]; if (v < bv) { bv = v; bi = i; } }
        } else if (task == 2) {
            for (int j = 0; j < 49; ++j) { float v = d2g[l * 49 + j]; if (v < bv) { bv = v; bi = j; } }
        } else {
            for (int i = 0; i < 49; ++i) { float v = d2g[i * 49 + l]; if (v < bv) { bv = v; bi = i; } }
        }
        mval[task][l] = bv; midx[task][l] = bi;
    }
    __syncthreads();
    if (l < 49) {
        float v = mval[task][l];
        int rank = 0;
        for (int k = 0; k < 49; ++k) {
            float u = mval[task][k];
            rank += (u < v) || (u == v && k < l);   // stable: matches lax.top_k ties
        }
        if (task == 0)      { if (rank < 20) atomicAdd(&ws[WS_S1], v); }
        else if (task == 1) { if (rank < 20) atomicAdd(&ws[WS_S2], v); }
        else if (task == 2) { if (rank < 20) atomicAdd(&ws[WS_S3], d2f[l * 49 + midx[2][l]]); }
        else                { if (rank < 4)  atomicAdd(&ws[WS_S4], d2f[midx[3][l] * 49 + l]); }
    }
}

// ---------------------------------------------------------------------------
// GK2: 128x128 Gram of z_a/z_b, K-split 64 chunks of 128 cols. Also emits the
// per-column sum/sumsq (disjoint columns -> plain stores). RED: disjoint Gram
// partials; else atomic.
// ---------------------------------------------------------------------------
template<bool RED>
__global__ __launch_bounds__(256) void gk2_gram(const float* __restrict__ za,
                                                const float* __restrict__ zb,
                                                float* __restrict__ ws,
                                                float* __restrict__ part)
{
    __shared__ float sx[128 * 68];
    const int tid = threadIdx.x;
    const int tensor = blockIdx.x >> 6;
    const int chunk  = blockIdx.x & 63;
    const float* X = (tensor ? zb : za) + chunk * 128;
    const int ty = tid >> 4, tx = tid & 15;
    const int q = tid >> 6, cc = tid & 63;

    float acc[8][8];
#pragma unroll
    for (int r = 0; r < 8; ++r)
#pragma unroll
        for (int c = 0; c < 8; ++c) acc[r][c] = 0.f;
    float colS[2] = {0.f, 0.f}, colQ[2] = {0.f, 0.f};

#pragma unroll
    for (int stage = 0; stage < 2; ++stage) {
        __syncthreads();
        for (int f = tid; f < 128 * 16; f += 256) {
            int row = f >> 4, c4 = f & 15;
            *(float4*)(sx + row * 68 + c4 * 4) =
                *(const float4*)(X + (size_t)row * DIM + stage * 64 + c4 * 4);
        }
        __syncthreads();
        for (int r = 0; r < 32; ++r) {
            float v = sx[(q * 32 + r) * 68 + cc];
            colS[stage] += v; colQ[stage] += v * v;
        }
        for (int k = 0; k < 64; k += 4) {
            float4 a4[8];
#pragma unroll
            for (int r = 0; r < 8; ++r) a4[r] = *(const float4*)(sx + (ty + 16 * r) * 68 + k);
#pragma unroll
            for (int c = 0; c < 8; ++c) {
                float4 b4 = *(const float4*)(sx + (tx + 16 * c) * 68 + k);
#pragma unroll
                for (int r = 0; r < 8; ++r)
                    acc[r][c] += a4[r].x * b4.x + a4[r].y * b4.y + a4[r].z * b4.z + a4[r].w * b4.w;
            }
        }
    }
    __syncthreads();
#pragma unroll
    for (int st = 0; st < 2; ++st) {
        sx[tid] = colS[st];
        sx[256 + tid] = colQ[st];
        __syncthreads();
        if (tid < 64) {
            float s  = sx[tid] + sx[64 + tid] + sx[128 + tid] + sx[192 + tid];
            float qq = sx[256 + tid] + sx[320 + tid] + sx[384 + tid] + sx[448 + tid];
            int col = chunk * 128 + st * 64 + tid;
            float* C = ws + COLS_OFF + tensor * 2 * DIM;
            C[col] = s; C[DIM + col] = qq;
        }
        __syncthreads();
    }
    if (RED) {
        float* P = part + (size_t)blockIdx.x * 16384;
#pragma unroll
        for (int r = 0; r < 8; ++r)
#pragma unroll
            for (int c = 0; c < 8; ++c)
                P[(ty + 16 * r) * 128 + (tx + 16 * c)] = acc[r][c];
    } else {
        float* G = ws + (tensor ? GRAMB_OFF : GRAMA_OFF);
#pragma unroll
        for (int r = 0; r < 8; ++r)
#pragma unroll
            for (int c = 0; c < 8; ++c)
                atomicAdd(&G[(ty + 16 * r) * 128 + (tx + 16 * c)], acc[r][c]);
    }
}

__global__ __launch_bounds__(256) void gk2_reduce(float* __restrict__ ws)
{
    const int g = blockIdx.x * 256 + threadIdx.x;   // 0..32767
    const int tensor = g >> 14;
    const int e = g & 16383;
    const float* P = ws + GK2PART_OFF + (size_t)tensor * 64 * 16384;
    float s = 0.f;
    for (int c = 0; c < 64; ++c) s += P[(size_t)c * 16384 + e];
    ws[(tensor ? GRAMB_OFF : GRAMA_OFF) + e] = s;
}

// ---------------------------------------------------------------------------
// GK1m: global MSE. GK1b: per-column std/relu/diag -> scalars.
// ---------------------------------------------------------------------------
__global__ __launch_bounds__(256) void gk1_mse(const float* __restrict__ za,
                                               const float* __restrict__ zb,
                                               float* __restrict__ ws)
{
    const size_t i0 = ((size_t)blockIdx.x * 256 + threadIdx.x) * 4;
    float ms = 0.f;
#pragma unroll
    for (int it = 0; it < 4; ++it) {
        size_t idx = i0 + (size_t)it * 262144;
        float4 a = *(const float4*)(za + idx);
        float4 b = *(const float4*)(zb + idx);
        float dx = a.x - b.x, dy = a.y - b.y, dz = a.z - b.z, dw = a.w - b.w;
        ms += dx * dx + dy * dy + dz * dz + dw * dw;
    }
    for (int o = 32; o; o >>= 1) ms += __shfl_xor(ms, o);
    if ((threadIdx.x & 63) == 0) atomicAdd(&ws[WS_MSE], ms);
}

__global__ __launch_bounds__(256) void gk1b(float* __restrict__ ws)
{
    const int col = blockIdx.x * 256 + threadIdx.x;
    float sa = ws[COLS_OFF + col];
    float qa = ws[COLS_OFF + DIM + col];
    float sb = ws[COLS_OFF + 2 * DIM + col];
    float qb = ws[COLS_OFF + 3 * DIM + col];
    float sA = qa - sa * sa * (1.0f / BATCH);
    float sB = qb - sb * sb * (1.0f / BATCH);
    float rA = fmaxf(0.f, 1.f - sqrtf(sA * (1.0f / (BATCH - 1)) + 1e-4f));
    float rB = fmaxf(0.f, 1.f - sqrtf(sB * (1.0f / (BATCH - 1)) + 1e-4f));
    float dA = sA * sA, dB = sB * sB;
    for (int o = 32; o; o >>= 1) {
        rA += __shfl_xor(rA, o);
        rB += __shfl_xor(rB, o);
        dA += __shfl_xor(dA, o);
        dB += __shfl_xor(dB, o);
    }
    if ((threadIdx.x & 63) == 0) {
        atomicAdd(&ws[WS_VARA],  rA);
        atomicAdd(&ws[WS_VARB],  rB);
        atomicAdd(&ws[WS_DIAGA], dA);
        atomicAdd(&ws[WS_DIAGB], dB);
    }
}

// ---------------------------------------------------------------------------
// GK3: ||K||_F^2 from the Gram. K = G - (r_i+r_j)/n + S/n^2.
// ---------------------------------------------------------------------------
__global__ __launch_bounds__(256) void gk3_cov(float* __restrict__ ws)
{
    __shared__ float r[128];
    __shared__ float sS;
    __shared__ float wrd[4];
    const int tid = threadIdx.x;
    const float* G = ws + (blockIdx.x ? GRAMB_OFF : GRAMA_OFF);
    if (tid < 128) {
        float s0 = 0.f, s1 = 0.f, s2 = 0.f, s3 = 0.f;
        for (int k = 0; k < 128; k += 4) {
            s0 += G[(k + 0) * 128 + tid];
            s1 += G[(k + 1) * 128 + tid];
            s2 += G[(k + 2) * 128 + tid];
            s3 += G[(k + 3) * 128 + tid];
        }
        r[tid] = (s0 + s1) + (s2 + s3);
    }
    __syncthreads();
    if (tid < 64) {
        float t = r[tid] + r[tid + 64];
        for (int o = 32; o; o >>= 1) t += __shfl_xor(t, o);
        if (tid == 0) sS = t;
    }
    __syncthreads();
    const float S = sS;
    float sk = 0.f;
    for (int e = tid; e < 16384; e += 256) {
        float K = G[e] - (r[e >> 7] + r[e & 127]) * (1.0f / 128.0f) + S * (1.0f / 16384.0f);
        sk += K * K;
    }
    for (int o = 32; o; o >>= 1) sk += __shfl_xor(sk, o);
    if ((tid & 63) == 0) wrd[tid >> 6] = sk;
    __syncthreads();
    if (tid == 0)
        ws[blockIdx.x ? WS_SK2B : WS_SK2A] = wrd[0] + wrd[1] + wrd[2] + wrd[3];
}

// ---------------------------------------------------------------------------
// GK4: final scalar assembly.
// ---------------------------------------------------------------------------
__global__ void gk4_final(const float* __restrict__ ws, float* __restrict__ out)
{
    if (threadIdx.x == 0) {
        float inv_g = ws[WS_MSE] * (1.0f / ((float)BATCH * (float)DIM));
        float varl  = 0.5f * (ws[WS_VARA] + ws[WS_VARB]) * (1.0f / (float)DIM);
        float cov   = (ws[WS_SK2A] - ws[WS_DIAGA] + ws[WS_SK2B] - ws[WS_DIAGB])
                      * (1.0f / (127.0f * 127.0f * (float)DIM));
        float gl = 25.0f * inv_g + 25.0f * varl + cov;
        float m20 = (float)BATCH * 20.0f * (float)DIM;
        float m4  = (float)BATCH * 4.0f  * (float)DIM;
        float invl = 0.5f * (ws[WS_S1] + ws[WS_S2] + ws[WS_S3]) / m20
                   + 0.5f * ws[WS_S4] / m4;
        out[0] = 0.25f * gl + 0.75f * (25.0f * invl);
    }
}

extern "C" void kernel_launch(void* const* d_in, const int* in_sizes, int n_in,
                              void* d_out, int out_size, void* d_ws, size_t ws_size,
                              hipStream_t stream)
{
    (void)in_sizes; (void)n_in; (void)out_size;
    const float* z_a = (const float*)d_in[0];
    const float* z_b = (const float*)d_in[1];
    const float* zla = (const float*)d_in[2];
    const float* zlb = (const float*)d_in[3];
    const float* ga  = (const float*)d_in[4];
    const float* gb  = (const float*)d_in[5];
    float* ws  = (float*)d_ws;
    float* out = (float*)d_out;

    const bool big = ws_size >= (size_t)WS_NEED_FLOATS * sizeof(float);

    if (big) {
        hipMemsetAsync(d_ws, 0, 16 * sizeof(float), stream);
        l1_gram<true><<<BATCH * 8, 256, 0, stream>>>(zla, zlb, ws + L1PART_BIG);
        gk2_gram<true><<<128, 256, 0, stream>>>(z_a, z_b, ws, ws + GK2PART_OFF);
        gk2_reduce<<<128, 256, 0, stream>>>(ws);
        gk1_mse<<<256, 256, 0, stream>>>(z_a, z_b, ws);
        gk1b<<<DIM / 256, 256, 0, stream>>>(ws);
        l2_match<true><<<BATCH, 256, 0, stream>>>(ga, gb, ws, ws + L1PART_BIG);
        gk3_cov<<<2, 256, 0, stream>>>(ws);
        gk4_final<<<1, 64, 0, stream>>>(ws, out);
    } else {
        hipMemsetAsync(d_ws, 0, (size_t)(L1PART_SMALL + BATCH * SLOT) * sizeof(float), stream);
        l1_gram<false><<<BATCH * 8, 256, 0, stream>>>(zla, zlb, ws + L1PART_SMALL);
        gk2_gram<false><<<128, 256, 0, stream>>>(z_a, z_b, ws, ws);
        gk1_mse<<<256, 256, 0, stream>>>(z_a, z_b, ws);
        gk1b<<<DIM / 256, 256, 0, stream>>>(ws);
        l2_match<false><<<BATCH, 256, 0, stream>>>(ga, gb, ws, ws + L1PART_SMALL);
        gk3_cov<<<2, 256, 0, stream>>>(ws);
        gk4_final<<<1, 64, 0, stream>>>(ws, out);
    }
}

// Round 5
// 209.761 us; speedup vs baseline: 1.1621x; 1.1621x over previous
//
#include <hip/hip_runtime.h>
#include <math.h>

#define BATCH 128
#define DIM   8192
#define HW    49
#define PAIRS 2401            // 49*49
#define SLOT  2512            // per-partial slot: 2401 G + 49 nA + 49 nB + pad

// ws float offsets
#define WS_MSE    0
#define WS_VARA   1
#define WS_VARB   2
#define WS_DIAGA  3
#define WS_DIAGB  4
#define WS_S1     5
#define WS_S2     6
#define WS_S3     7
#define WS_S4     8
#define WS_SK2A   9
#define WS_SK2B   10
#define COLS_OFF    16                         // sa,qa,sb,qb: 4*DIM
#define GRAMA_OFF   32784
#define GRAMB_OFF   49168
#define GK2PART_OFF 65552                      // 128 blocks * 16384
#define L1PART_BIG  2162704                    // 256 blocks * SLOT
#define WS_NEED_FLOATS (L1PART_BIG + 256 * SLOT)
#define L1PART_SMALL 65552                     // fallback: 128 batch slots (atomic)

typedef __attribute__((ext_vector_type(8))) short bf16x8;
typedef __attribute__((ext_vector_type(4))) float f32x4;

__device__ __forceinline__ unsigned cvtpk(float lo, float hi) {
    unsigned r;
    asm("v_cvt_pk_bf16_f32 %0, %1, %2" : "=v"(r) : "v"(lo), "v"(hi));
    return r;
}
__device__ __forceinline__ float sq4(float4 v) {
    return v.x * v.x + v.y * v.y + v.z * v.z + v.w * v.w;
}

// ---------------------------------------------------------------------------
// L1: per-batch padded 64x64 Gram of 49x8192 features via bf16 MFMA.
// grid = 128 batches * 2 K-halves = 256 blocks (1/CU), 512 thr (8 waves).
// DRAM-friendliness is the whole design: each load instruction is one WAVE
// reading one row-strip of BK=256 floats = 1KB CONTIGUOUS (lane*16B), so the
// memory system sees 1KB runs instead of the 128-512B strided combs that
// thrashed rounds 1-4 (0.8-2.5 TB/s).
// Stage loop (16 stages of BK=256): T14 issue-early/write-late: issue ~13
// 1KB loads to regs -> compute current tile (wave w does K-step w: 8
// ds_read_b128 + 16 MFMA) -> barrier -> cvt fp32->bf16 + swizzled ds_write
// (vmcnt waits fold here; loads were airborne across compute+barrier) ->
// barrier. Single 50KB LDS tile [2][49][512B bf16], swizzle (row&31)<<4.
// Epilogue: 8-wave LDS-atomic reduce -> per-block partial slot (RED) or
// per-batch atomics (fallback).
// ---------------------------------------------------------------------------
template<bool RED>
__global__ __launch_bounds__(512) void l1_gram(const float* __restrict__ za,
                                               const float* __restrict__ zb,
                                               float* __restrict__ l1part)
{
    __shared__ unsigned char tile[50176];   // A rows at 0, B rows at +25088

    const int tid  = threadIdx.x;
    const int wv   = tid >> 6;        // 0..7
    const int lane = tid & 63;
    const int r = lane & 15, g = lane >> 4;
    const int batch = blockIdx.x >> 1;
    const int kh    = blockIdx.x & 1;

    const float* Az = za + (size_t)batch * HW * DIM + kh * 4096;
    const float* Bz = zb + (size_t)batch * HW * DIM + kh * 4096;

    // staging units: 98 (tensor,row) strips; wave w owns u = w, w+8, ...
    const float* uptr[13];
    int   wbyte[13];                  // precomputed swizzled LDS write addr
    float nrm[13];
#pragma unroll
    for (int i = 0; i < 13; ++i) {
        int u = wv + 8 * i;
        nrm[i] = 0.f;
        if (u < 98) {
            int tens = (u >= 49) ? 1 : 0;
            int row  = u - 49 * tens;
            uptr[i]  = (tens ? Bz : Az) + (size_t)row * DIM + lane * 4;
            wbyte[i] = tens * 25088 + row * 512 + ((lane * 8) ^ ((row & 31) << 4));
        } else { uptr[i] = Az + lane * 4; wbyte[i] = -1; }
    }

    // fragment read addrs: wave w = K-step w; row=lane&15(+16m), k=(lane>>4)*8+e
    int abyte[4], bbyte[4];
    const int kbyte = wv * 64 + g * 16;
#pragma unroll
    for (int m = 0; m < 4; ++m) {
        int rowm = 16 * m + r; if (rowm > 48) rowm = 48;   // pad rows clamp
        int sw = (rowm & 31) << 4;
        abyte[m] = rowm * 512 + (kbyte ^ sw);
        bbyte[m] = 25088 + rowm * 512 + (kbyte ^ sw);
    }

    f32x4 acc[4][4];
#pragma unroll
    for (int m = 0; m < 4; ++m)
#pragma unroll
        for (int n = 0; n < 4; ++n) acc[m][n] = (f32x4){0.f, 0.f, 0.f, 0.f};

    float4 XR[13];

#define L1_ISSUE(s) do {                                                      \
    _Pragma("unroll") for (int i = 0; i < 13; ++i)                            \
        if (wbyte[i] >= 0) XR[i] = *(const float4*)(uptr[i] + (size_t)(s) * 256); \
    } while (0)

#define L1_WRITE() do {                                                       \
    _Pragma("unroll") for (int i = 0; i < 13; ++i)                            \
        if (wbyte[i] >= 0) {                                                  \
            nrm[i] += sq4(XR[i]);                                             \
            *(uint2*)(tile + wbyte[i]) =                                      \
                make_uint2(cvtpk(XR[i].x, XR[i].y), cvtpk(XR[i].z, XR[i].w)); \
        } } while (0)

#define L1_COMPUTE() do {                                                     \
        bf16x8 fa0 = *(const bf16x8*)(tile + abyte[0]);                       \
        bf16x8 fa1 = *(const bf16x8*)(tile + abyte[1]);                       \
        bf16x8 fa2 = *(const bf16x8*)(tile + abyte[2]);                       \
        bf16x8 fa3 = *(const bf16x8*)(tile + abyte[3]);                       \
        bf16x8 fb0 = *(const bf16x8*)(tile + bbyte[0]);                       \
        bf16x8 fb1 = *(const bf16x8*)(tile + bbyte[1]);                       \
        bf16x8 fb2 = *(const bf16x8*)(tile + bbyte[2]);                       \
        bf16x8 fb3 = *(const bf16x8*)(tile + bbyte[3]);                       \
        acc[0][0] = __builtin_amdgcn_mfma_f32_16x16x32_bf16(fa0, fb0, acc[0][0], 0, 0, 0); \
        acc[0][1] = __builtin_amdgcn_mfma_f32_16x16x32_bf16(fa0, fb1, acc[0][1], 0, 0, 0); \
        acc[0][2] = __builtin_amdgcn_mfma_f32_16x16x32_bf16(fa0, fb2, acc[0][2], 0, 0, 0); \
        acc[0][3] = __builtin_amdgcn_mfma_f32_16x16x32_bf16(fa0, fb3, acc[0][3], 0, 0, 0); \
        acc[1][0] = __builtin_amdgcn_mfma_f32_16x16x32_bf16(fa1, fb0, acc[1][0], 0, 0, 0); \
        acc[1][1] = __builtin_amdgcn_mfma_f32_16x16x32_bf16(fa1, fb1, acc[1][1], 0, 0, 0); \
        acc[1][2] = __builtin_amdgcn_mfma_f32_16x16x32_bf16(fa1, fb2, acc[1][2], 0, 0, 0); \
        acc[1][3] = __builtin_amdgcn_mfma_f32_16x16x32_bf16(fa1, fb3, acc[1][3], 0, 0, 0); \
        acc[2][0] = __builtin_amdgcn_mfma_f32_16x16x32_bf16(fa2, fb0, acc[2][0], 0, 0, 0); \
        acc[2][1] = __builtin_amdgcn_mfma_f32_16x16x32_bf16(fa2, fb1, acc[2][1], 0, 0, 0); \
        acc[2][2] = __builtin_amdgcn_mfma_f32_16x16x32_bf16(fa2, fb2, acc[2][2], 0, 0, 0); \
        acc[2][3] = __builtin_amdgcn_mfma_f32_16x16x32_bf16(fa2, fb3, acc[2][3], 0, 0, 0); \
        acc[3][0] = __builtin_amdgcn_mfma_f32_16x16x32_bf16(fa3, fb0, acc[3][0], 0, 0, 0); \
        acc[3][1] = __builtin_amdgcn_mfma_f32_16x16x32_bf16(fa3, fb1, acc[3][1], 0, 0, 0); \
        acc[3][2] = __builtin_amdgcn_mfma_f32_16x16x32_bf16(fa3, fb2, acc[3][2], 0, 0, 0); \
        acc[3][3] = __builtin_amdgcn_mfma_f32_16x16x32_bf16(fa3, fb3, acc[3][3], 0, 0, 0); \
    } while (0)

    // prologue: stage 0
    L1_ISSUE(0);
    L1_WRITE();
    __syncthreads();

#pragma unroll 1
    for (int s = 0; s < 16; ++s) {
        if (s < 15) {
            L1_ISSUE(s + 1);                     // 1KB-contiguous loads airborne
            __builtin_amdgcn_sched_barrier(0);   // don't sink below compute
        }
        L1_COMPUTE();                            // tile s
        if (s < 15) {
            __syncthreads();                     // all waves done reading tile s
            L1_WRITE();                          // vmcnt waits fold here
            __syncthreads();                     // tile s+1 visible
        }
    }
#undef L1_ISSUE
#undef L1_WRITE
#undef L1_COMPUTE

    // ---- epilogue: reduce 8 waves via LDS (reuse tile as fp32 scratch) ----
    __syncthreads();
    float* red = (float*)tile;
    for (int i = tid; i < 4096; i += 512) red[i] = 0.f;
    __syncthreads();
#pragma unroll
    for (int m = 0; m < 4; ++m)
#pragma unroll
        for (int n = 0; n < 4; ++n)
#pragma unroll
            for (int rr = 0; rr < 4; ++rr)
                atomicAdd(&red[(16 * m + g * 4 + rr) * 64 + 16 * n + r], acc[m][n][rr]);
    __syncthreads();

    float* gout = l1part + (size_t)(RED ? blockIdx.x : batch) * SLOT;
    for (int e = tid; e < PAIRS; e += 512) {
        int row = e / 49, col = e - row * 49;
        float v = red[row * 64 + col];
        if (RED) gout[e] = v; else atomicAdd(&gout[e], v);
    }
    // norms: whole wave loaded each unit -> full 64-lane shfl reduce
#pragma unroll
    for (int i = 0; i < 13; ++i) {
        int u = wv + 8 * i;
        if (u < 98) {
            float v = nrm[i];
            v += __shfl_xor(v, 1);  v += __shfl_xor(v, 2);
            v += __shfl_xor(v, 4);  v += __shfl_xor(v, 8);
            v += __shfl_xor(v, 16); v += __shfl_xor(v, 32);
            if (lane == 0) {
                int tens = (u >= 49) ? 1 : 0;
                int row  = u - 49 * tens;
                int off  = PAIRS + tens * HW + row;
                if (RED) gout[off] = v; else atomicAdd(&gout[off], v);
            }
        }
    }
}

// ---------------------------------------------------------------------------
// L2: per-batch matching. RED mode folds the 2-way K-half reduction of the
// l1 partial Grams/norms into the d2f build. Selection logic unchanged.
// ---------------------------------------------------------------------------
template<bool RED>
__global__ __launch_bounds__(256) void l2_match(const float* __restrict__ ga,
                                                const float* __restrict__ gb,
                                                float* __restrict__ ws,
                                                const float* __restrict__ l1part)
{
    __shared__ float d2f[PAIRS];
    __shared__ float d2g[PAIRS];
    __shared__ float nAs[49], nBs[49];
    __shared__ float gax[49], gay[49], gbx[49], gby[49];
    __shared__ float mval[4][49];
    __shared__ int   midx[4][49];

    const int tid = threadIdx.x;
    const int batch = blockIdx.x;
    const float* P0 = l1part + (size_t)batch * (RED ? (2 * SLOT) : SLOT);

    auto rd = [&](int off) -> float {
        if (!RED) return P0[off];
        return P0[off] + P0[SLOT + off];
    };

    if (tid < 49) nAs[tid] = rd(PAIRS + tid);
    else if (tid >= 64 && tid < 113) nBs[tid - 64] = rd(PAIRS + 49 + (tid - 64));
    if (tid >= 128 && tid < 177) {
        int i = tid - 128;
        gax[i] = ga[batch * 98 + i * 2];
        gay[i] = ga[batch * 98 + i * 2 + 1];
    } else if (tid >= 192 && tid < 241) {
        int i = tid - 192;
        gbx[i] = gb[batch * 98 + i * 2];
        gby[i] = gb[batch * 98 + i * 2 + 1];
    }
    __syncthreads();
    for (int e = tid; e < PAIRS; e += 256) {
        int i = e / 49, j = e - i * 49;
        d2f[e] = nAs[i] + nBs[j] - 2.0f * rd(e);
        float dx = gax[i] - gbx[j], dy = gay[i] - gby[j];
        d2g[e] = dx * dx + dy * dy;
    }
    __syncthreads();
    const int task = tid >> 6, l = tid & 63;
    if (l < 49) {
        float bv = 3.0e38f; int bi = 0;
        if (task == 0) {
            for (int j = 0; j < 49; ++j) { float v = d2f[l * 49 + j]; if (v < bv) { bv = v; bi = j; } }
        } else if (task == 1) {
            for (int i = 0; i < 49; ++i) { float v = d2f[i * 49 + l]; if (v < bv) { bv = v; bi = i; } }
        } else if (task == 2) {
            for (int j = 0; j < 49; ++j) { float v = d2g[l * 49 + j]; if (v < bv) { bv = v; bi = j; } }
        } else {
            for (int i = 0; i < 49; ++i) { float v = d2g[i * 49 + l]; if (v < bv) { bv = v; bi = i; } }
        }
        mval[task][l] = bv; midx[task][l] = bi;
    }
    __syncthreads();
    if (l < 49) {
        float v = mval[task][l];
        int rank = 0;
        for (int k = 0; k < 49; ++k) {
            float u = mval[task][k];
            rank += (u < v) || (u == v && k < l);   // stable: matches lax.top_k ties
        }
        if (task == 0)      { if (rank < 20) atomicAdd(&ws[WS_S1], v); }
        else if (task == 1) { if (rank < 20) atomicAdd(&ws[WS_S2], v); }
        else if (task == 2) { if (rank < 20) atomicAdd(&ws[WS_S3], d2f[l * 49 + midx[2][l]]); }
        else                { if (rank < 4)  atomicAdd(&ws[WS_S4], d2f[midx[3][l] * 49 + l]); }
    }
}

// ---------------------------------------------------------------------------
// GK2: 128x128 Gram of z_a/z_b, K-split 64 chunks of 128 cols + per-column
// sum/sumsq (disjoint -> plain stores). RED: disjoint partials; else atomic.
// ---------------------------------------------------------------------------
template<bool RED>
__global__ __launch_bounds__(256) void gk2_gram(const float* __restrict__ za,
                                                const float* __restrict__ zb,
                                                float* __restrict__ ws,
                                                float* __restrict__ part)
{
    __shared__ float sx[128 * 68];
    const int tid = threadIdx.x;
    const int tensor = blockIdx.x >> 6;
    const int chunk  = blockIdx.x & 63;
    const float* X = (tensor ? zb : za) + chunk * 128;
    const int ty = tid >> 4, tx = tid & 15;
    const int q = tid >> 6, cc = tid & 63;

    float acc[8][8];
#pragma unroll
    for (int r = 0; r < 8; ++r)
#pragma unroll
        for (int c = 0; c < 8; ++c) acc[r][c] = 0.f;
    float colS[2] = {0.f, 0.f}, colQ[2] = {0.f, 0.f};

#pragma unroll
    for (int stage = 0; stage < 2; ++stage) {
        __syncthreads();
        for (int f = tid; f < 128 * 16; f += 256) {
            int row = f >> 4, c4 = f & 15;
            *(float4*)(sx + row * 68 + c4 * 4) =
                *(const float4*)(X + (size_t)row * DIM + stage * 64 + c4 * 4);
        }
        __syncthreads();
        for (int r = 0; r < 32; ++r) {
            float v = sx[(q * 32 + r) * 68 + cc];
            colS[stage] += v; colQ[stage] += v * v;
        }
        for (int k = 0; k < 64; k += 4) {
            float4 a4[8];
#pragma unroll
            for (int r = 0; r < 8; ++r) a4[r] = *(const float4*)(sx + (ty + 16 * r) * 68 + k);
#pragma unroll
            for (int c = 0; c < 8; ++c) {
                float4 b4 = *(const float4*)(sx + (tx + 16 * c) * 68 + k);
#pragma unroll
                for (int r = 0; r < 8; ++r)
                    acc[r][c] += a4[r].x * b4.x + a4[r].y * b4.y + a4[r].z * b4.z + a4[r].w * b4.w;
            }
        }
    }
    __syncthreads();
#pragma unroll
    for (int st = 0; st < 2; ++st) {
        sx[tid] = colS[st];
        sx[256 + tid] = colQ[st];
        __syncthreads();
        if (tid < 64) {
            float s  = sx[tid] + sx[64 + tid] + sx[128 + tid] + sx[192 + tid];
            float qq = sx[256 + tid] + sx[320 + tid] + sx[384 + tid] + sx[448 + tid];
            int col = chunk * 128 + st * 64 + tid;
            float* C = ws + COLS_OFF + tensor * 2 * DIM;
            C[col] = s; C[DIM + col] = qq;
        }
        __syncthreads();
    }
    if (RED) {
        float* P = part + (size_t)blockIdx.x * 16384;
#pragma unroll
        for (int r = 0; r < 8; ++r)
#pragma unroll
            for (int c = 0; c < 8; ++c)
                P[(ty + 16 * r) * 128 + (tx + 16 * c)] = acc[r][c];
    } else {
        float* G = ws + (tensor ? GRAMB_OFF : GRAMA_OFF);
#pragma unroll
        for (int r = 0; r < 8; ++r)
#pragma unroll
            for (int c = 0; c < 8; ++c)
                atomicAdd(&G[(ty + 16 * r) * 128 + (tx + 16 * c)], acc[r][c]);
    }
}

__global__ __launch_bounds__(256) void gk2_reduce(float* __restrict__ ws)
{
    const int g = blockIdx.x * 256 + threadIdx.x;   // 0..32767
    const int tensor = g >> 14;
    const int e = g & 16383;
    const float* P = ws + GK2PART_OFF + (size_t)tensor * 64 * 16384;
    float s = 0.f;
    for (int c = 0; c < 64; ++c) s += P[(size_t)c * 16384 + e];
    ws[(tensor ? GRAMB_OFF : GRAMA_OFF) + e] = s;
}

// ---------------------------------------------------------------------------
// GK1m: global MSE. GK1b: per-column std/relu/diag -> scalars.
// ---------------------------------------------------------------------------
__global__ __launch_bounds__(256) void gk1_mse(const float* __restrict__ za,
                                               const float* __restrict__ zb,
                                               float* __restrict__ ws)
{
    const size_t i0 = ((size_t)blockIdx.x * 256 + threadIdx.x) * 4;
    float ms = 0.f;
#pragma unroll
    for (int it = 0; it < 4; ++it) {
        size_t idx = i0 + (size_t)it * 262144;
        float4 a = *(const float4*)(za + idx);
        float4 b = *(const float4*)(zb + idx);
        float dx = a.x - b.x, dy = a.y - b.y, dz = a.z - b.z, dw = a.w - b.w;
        ms += dx * dx + dy * dy + dz * dz + dw * dw;
    }
    for (int o = 32; o; o >>= 1) ms += __shfl_xor(ms, o);
    if ((threadIdx.x & 63) == 0) atomicAdd(&ws[WS_MSE], ms);
}

__global__ __launch_bounds__(256) void gk1b(float* __restrict__ ws)
{
    const int col = blockIdx.x * 256 + threadIdx.x;
    float sa = ws[COLS_OFF + col];
    float qa = ws[COLS_OFF + DIM + col];
    float sb = ws[COLS_OFF + 2 * DIM + col];
    float qb = ws[COLS_OFF + 3 * DIM + col];
    float sA = qa - sa * sa * (1.0f / BATCH);
    float sB = qb - sb * sb * (1.0f / BATCH);
    float rA = fmaxf(0.f, 1.f - sqrtf(sA * (1.0f / (BATCH - 1)) + 1e-4f));
    float rB = fmaxf(0.f, 1.f - sqrtf(sB * (1.0f / (BATCH - 1)) + 1e-4f));
    float dA = sA * sA, dB = sB * sB;
    for (int o = 32; o; o >>= 1) {
        rA += __shfl_xor(rA, o);
        rB += __shfl_xor(rB, o);
        dA += __shfl_xor(dA, o);
        dB += __shfl_xor(dB, o);
    }
    if ((threadIdx.x & 63) == 0) {
        atomicAdd(&ws[WS_VARA],  rA);
        atomicAdd(&ws[WS_VARB],  rB);
        atomicAdd(&ws[WS_DIAGA], dA);
        atomicAdd(&ws[WS_DIAGB], dB);
    }
}

// ---------------------------------------------------------------------------
// GK3: ||K||_F^2 from the Gram. K = G - (r_i+r_j)/n + S/n^2.
// ---------------------------------------------------------------------------
__global__ __launch_bounds__(256) void gk3_cov(float* __restrict__ ws)
{
    __shared__ float r[128];
    __shared__ float sS;
    __shared__ float wrd[4];
    const int tid = threadIdx.x;
    const float* G = ws + (blockIdx.x ? GRAMB_OFF : GRAMA_OFF);
    if (tid < 128) {
        float s0 = 0.f, s1 = 0.f, s2 = 0.f, s3 = 0.f;
        for (int k = 0; k < 128; k += 4) {
            s0 += G[(k + 0) * 128 + tid];
            s1 += G[(k + 1) * 128 + tid];
            s2 += G[(k + 2) * 128 + tid];
            s3 += G[(k + 3) * 128 + tid];
        }
        r[tid] = (s0 + s1) + (s2 + s3);
    }
    __syncthreads();
    if (tid < 64) {
        float t = r[tid] + r[tid + 64];
        for (int o = 32; o; o >>= 1) t += __shfl_xor(t, o);
        if (tid == 0) sS = t;
    }
    __syncthreads();
    const float S = sS;
    float sk = 0.f;
    for (int e = tid; e < 16384; e += 256) {
        float K = G[e] - (r[e >> 7] + r[e & 127]) * (1.0f / 128.0f) + S * (1.0f / 16384.0f);
        sk += K * K;
    }
    for (int o = 32; o; o >>= 1) sk += __shfl_xor(sk, o);
    if ((tid & 63) == 0) wrd[tid >> 6] = sk;
    __syncthreads();
    if (tid == 0)
        ws[blockIdx.x ? WS_SK2B : WS_SK2A] = wrd[0] + wrd[1] + wrd[2] + wrd[3];
}

// ---------------------------------------------------------------------------
// GK4: final scalar assembly.
// ---------------------------------------------------------------------------
__global__ void gk4_final(const float* __restrict__ ws, float* __restrict__ out)
{
    if (threadIdx.x == 0) {
        float inv_g = ws[WS_MSE] * (1.0f / ((float)BATCH * (float)DIM));
        float varl  = 0.5f * (ws[WS_VARA] + ws[WS_VARB]) * (1.0f / (float)DIM);
        float cov   = (ws[WS_SK2A] - ws[WS_DIAGA] + ws[WS_SK2B] - ws[WS_DIAGB])
                      * (1.0f / (127.0f * 127.0f * (float)DIM));
        float gl = 25.0f * inv_g + 25.0f * varl + cov;
        float m20 = (float)BATCH * 20.0f * (float)DIM;
        float m4  = (float)BATCH * 4.0f  * (float)DIM;
        float invl = 0.5f * (ws[WS_S1] + ws[WS_S2] + ws[WS_S3]) / m20
                   + 0.5f * ws[WS_S4] / m4;
        out[0] = 0.25f * gl + 0.75f * (25.0f * invl);
    }
}

extern "C" void kernel_launch(void* const* d_in, const int* in_sizes, int n_in,
                              void* d_out, int out_size, void* d_ws, size_t ws_size,
                              hipStream_t stream)
{
    (void)in_sizes; (void)n_in; (void)out_size;
    const float* z_a = (const float*)d_in[0];
    const float* z_b = (const float*)d_in[1];
    const float* zla = (const float*)d_in[2];
    const float* zlb = (const float*)d_in[3];
    const float* ga  = (const float*)d_in[4];
    const float* gb  = (const float*)d_in[5];
    float* ws  = (float*)d_ws;
    float* out = (float*)d_out;

    const bool big = ws_size >= (size_t)WS_NEED_FLOATS * sizeof(float);

    if (big) {
        hipMemsetAsync(d_ws, 0, 16 * sizeof(float), stream);
        l1_gram<true><<<BATCH * 2, 512, 0, stream>>>(zla, zlb, ws + L1PART_BIG);
        gk2_gram<true><<<128, 256, 0, stream>>>(z_a, z_b, ws, ws + GK2PART_OFF);
        gk2_reduce<<<128, 256, 0, stream>>>(ws);
        gk1_mse<<<256, 256, 0, stream>>>(z_a, z_b, ws);
        gk1b<<<DIM / 256, 256, 0, stream>>>(ws);
        l2_match<true><<<BATCH, 256, 0, stream>>>(ga, gb, ws, ws + L1PART_BIG);
        gk3_cov<<<2, 256, 0, stream>>>(ws);
        gk4_final<<<1, 64, 0, stream>>>(ws, out);
    } else {
        hipMemsetAsync(d_ws, 0, (size_t)(L1PART_SMALL + BATCH * SLOT) * sizeof(float), stream);
        l1_gram<false><<<BATCH * 2, 512, 0, stream>>>(zla, zlb, ws + L1PART_SMALL);
        gk2_gram<false><<<128, 256, 0, stream>>>(z_a, z_b, ws, ws);
        gk1_mse<<<256, 256, 0, stream>>>(z_a, z_b, ws);
        gk1b<<<DIM / 256, 256, 0, stream>>>(ws);
        l2_match<false><<<BATCH, 256, 0, stream>>>(ga, gb, ws, ws + L1PART_SMALL);
        gk3_cov<<<2, 256, 0, stream>>>(ws);
        gk4_final<<<1, 64, 0, stream>>>(ws, out);
    }
}

// Round 6
// 184.208 us; speedup vs baseline: 1.3234x; 1.1387x over previous
//
#include <hip/hip_runtime.h>
#include <math.h>

#define BATCH 128
#define DIM   8192
#define HW    49
#define PAIRS 2401            // 49*49
#define SLOT  2512            // per-partial slot: 2401 G + 49 nA + 49 nB + pad

// ws float offsets
#define WS_MSE    0
#define WS_VARA   1
#define WS_VARB   2
#define WS_DIAGA  3
#define WS_DIAGB  4
#define WS_S1     5
#define WS_S2     6
#define WS_S3     7
#define WS_S4     8
#define WS_SK2A   9
#define WS_SK2B   10
#define COLS_OFF    16                         // sa,qa,sb,qb: 4*DIM
#define GRAMA_OFF   32784
#define GRAMB_OFF   49168
#define GK2PART_OFF 65552                      // 128 blocks * 16384
#define L1PART_BIG  2162704                    // 1024 blocks * SLOT
#define WS_NEED_FLOATS (L1PART_BIG + 1024 * SLOT)   // ~19 MB
#define L1PART_SMALL 65552                     // fallback: 128 batch slots (atomic)

typedef __attribute__((ext_vector_type(8))) short bf16x8;
typedef __attribute__((ext_vector_type(4))) float f32x4;

__device__ __forceinline__ unsigned cvtpk(float lo, float hi) {
    unsigned r;
    asm("v_cvt_pk_bf16_f32 %0, %1, %2" : "=v"(r) : "v"(lo), "v"(hi));
    return r;
}
__device__ __forceinline__ bf16x8 cvt8(f32x4 a, f32x4 b) {
    union { unsigned u[4]; bf16x8 v; } r;
    r.u[0] = cvtpk(a.x, a.y); r.u[1] = cvtpk(a.z, a.w);
    r.u[2] = cvtpk(b.x, b.y); r.u[3] = cvtpk(b.z, b.w);
    return r.v;
}
__device__ __forceinline__ f32x4 ld4(const unsigned char* p) {
    return *(const f32x4*)p;
}
// DMA global->LDS, 16B per lane, lane i lands at ldsbase + i*16. No VGPR dest
// => the compiler CANNOT sink/serialize these (rounds 3-5 failure mode).
__device__ __forceinline__ void gload16(const float* g, unsigned char* l) {
    __builtin_amdgcn_global_load_lds(
        (const __attribute__((address_space(1))) void*)g,
        (__attribute__((address_space(3))) void*)l, 16, 0, 0);
}
// 16B-slot permutation within a 256B row: bijective per 16 consecutive rows.
__device__ __forceinline__ int permr(int r) { return ((r & 7) << 1) | ((r >> 3) & 1); }

// ---------------------------------------------------------------------------
// L1: per-batch padded 64x64 Gram of 49x8192 features via bf16 MFMA.
// grid = 128 batches * 8 K-splits (K=1024/block), 256 thr (4 waves), 3/CU.
// Staging is global_load_lds DMA of fp32 (BK=64 = 256B rows), double-buffered
// 2x25KB LDS, 2-phase: {issue DMA for stage s+1 -> compute stage s -> barrier
// (vmcnt drains)}. LDS dest is linear (DMA constraint); the GLOBAL source is
// per-lane pre-permuted with permr so fragment ds_read_b128s are 2-way max.
// Fragments read fp32 from LDS, cvt->bf16 in-reg, 8 MFMA/wave/stage into the
// wave's own 32x32 quadrant (disjoint -> storeout needs no reduction).
// Row norms: exact fp32 sums from LDS (slot-permutation invariant).
// ---------------------------------------------------------------------------
template<bool RED>
__global__ __launch_bounds__(256, 3) void l1_gram(const float* __restrict__ za,
                                                  const float* __restrict__ zb,
                                                  float* __restrict__ l1part)
{
    __shared__ __align__(16) unsigned char buf[2][25600];   // 100 rows x 256B each

    const int tid = threadIdx.x;
    const int l = tid & 63, w = tid >> 6;
    const int fr = l & 15, kg = l >> 4;
    const int batch = blockIdx.x >> 3;
    const int ks    = blockIdx.x & 7;

    const float* Az = za + (size_t)batch * HW * DIM + (size_t)ks * 1024;
    const float* Bz = zb + (size_t)batch * HW * DIM + (size_t)ks * 1024;

    // ---- staging descriptors: 25 DMA instrs (4 rows each), wave w owns j=w+4i
    const float* gp[7];
    int jb[7];
#pragma unroll
    for (int i = 0; i < 7; ++i) {
        int j = w + 4 * i;
        if (j < 25) {
            int row = 4 * j + kg;                 // LDS row this lane feeds
            int slot = fr ^ permr(row);           // pre-permuted global 16B slot
            const float* p;
            if (row < 49)      p = Az + (size_t)row * DIM + slot * 4;
            else if (row < 98) p = Bz + (size_t)(row - 49) * DIM + slot * 4;
            else               p = Az + fr * 4;   // scrap rows 98/99: dummy valid addr
            gp[i] = p;
            jb[i] = j * 1024;
        } else { gp[i] = Az; jb[i] = -1; }
    }

    // ---- fragment LDS offsets (A rows 0-48, B rows 49-97; clamp pad rows)
    const int wr = w >> 1, wc = w & 1;
    int aoff[2][2][2], boff[2][2][2];
#pragma unroll
    for (int m = 0; m < 2; ++m)
#pragma unroll
        for (int kss = 0; kss < 2; ++kss) {
            int ar = wr * 32 + m * 16 + fr; if (ar > 48) ar = 48;
            int br = wc * 32 + m * 16 + fr; if (br > 48) br = 48;
            int lrb = 49 + br;
            int sb = kss * 8 + kg * 2;
            aoff[m][kss][0] = ar * 256 + ((sb)     ^ permr(ar)) * 16;
            aoff[m][kss][1] = ar * 256 + ((sb + 1) ^ permr(ar)) * 16;
            boff[m][kss][0] = lrb * 256 + ((sb)     ^ permr(lrb)) * 16;
            boff[m][kss][1] = lrb * 256 + ((sb + 1) ^ permr(lrb)) * 16;
        }

    // ---- norm descriptors: thread owns rows (tid>>4)+16i, slot tid&15
    int noff[7];
    float nacc[7];
#pragma unroll
    for (int i = 0; i < 7; ++i) {
        int rown = (tid >> 4) + 16 * i;
        noff[i] = (rown < 98) ? rown * 256 + (tid & 15) * 16 : -1;
        nacc[i] = 0.f;
    }

    f32x4 acc[2][2];
#pragma unroll
    for (int m = 0; m < 2; ++m)
#pragma unroll
        for (int n = 0; n < 2; ++n) acc[m][n] = (f32x4){0.f, 0.f, 0.f, 0.f};

#define L1_STAGE(pb, s) do {                                                   \
    _Pragma("unroll") for (int i = 0; i < 7; ++i)                              \
        if (jb[i] >= 0) gload16(gp[i] + (size_t)(s) * 64, &buf[pb][jb[i]]);    \
    } while (0)

#define L1_COMPUTE(pb) do {                                                    \
    const unsigned char* B_ = buf[pb];                                         \
    _Pragma("unroll") for (int kss = 0; kss < 2; ++kss) {                      \
        bf16x8 fa0 = cvt8(ld4(B_ + aoff[0][kss][0]), ld4(B_ + aoff[0][kss][1])); \
        bf16x8 fa1 = cvt8(ld4(B_ + aoff[1][kss][0]), ld4(B_ + aoff[1][kss][1])); \
        bf16x8 fb0 = cvt8(ld4(B_ + boff[0][kss][0]), ld4(B_ + boff[0][kss][1])); \
        bf16x8 fb1 = cvt8(ld4(B_ + boff[1][kss][0]), ld4(B_ + boff[1][kss][1])); \
        acc[0][0] = __builtin_amdgcn_mfma_f32_16x16x32_bf16(fa0, fb0, acc[0][0], 0, 0, 0); \
        acc[0][1] = __builtin_amdgcn_mfma_f32_16x16x32_bf16(fa0, fb1, acc[0][1], 0, 0, 0); \
        acc[1][0] = __builtin_amdgcn_mfma_f32_16x16x32_bf16(fa1, fb0, acc[1][0], 0, 0, 0); \
        acc[1][1] = __builtin_amdgcn_mfma_f32_16x16x32_bf16(fa1, fb1, acc[1][1], 0, 0, 0); \
    }                                                                          \
    _Pragma("unroll") for (int i = 0; i < 7; ++i)                              \
        if (noff[i] >= 0) {                                                    \
            f32x4 v = ld4(B_ + noff[i]);                                       \
            nacc[i] += v.x * v.x + v.y * v.y + v.z * v.z + v.w * v.w;          \
        }                                                                      \
    } while (0)

    L1_STAGE(0, 0);
    __syncthreads();                           // vmcnt drains: stage 0 resident
#pragma unroll 1
    for (int s = 0; s < 16; s += 2) {
        L1_STAGE(1, s + 1);                    // DMA airborne during compute
        __builtin_amdgcn_sched_barrier(0);
        L1_COMPUTE(0);                         // stage s
        __syncthreads();                       // drains stage s+1 DMA
        if (s + 2 < 16) L1_STAGE(0, s + 2);
        __builtin_amdgcn_sched_barrier(0);
        L1_COMPUTE(1);                         // stage s+1
        __syncthreads();
    }
#undef L1_STAGE
#undef L1_COMPUTE

    // ---- epilogue: quadrants are disjoint -> direct stores (RED) / atomics
    float* gout = l1part + (size_t)(RED ? blockIdx.x : batch) * SLOT;
#pragma unroll
    for (int m = 0; m < 2; ++m)
#pragma unroll
        for (int n = 0; n < 2; ++n)
#pragma unroll
            for (int rr = 0; rr < 4; ++rr) {
                int grow = wr * 32 + m * 16 + kg * 4 + rr;
                int gcol = wc * 32 + n * 16 + fr;
                if (grow < HW && gcol < HW) {
                    float v = acc[m][n][rr];
                    if (RED) gout[grow * HW + gcol] = v;
                    else atomicAdd(&gout[grow * HW + gcol], v);
                }
            }
    // norms: 16-lane groups share a row set -> shfl tree; rows 0-48=A, 49-97=B
    // SLOT layout has nA then nB contiguous => offset PAIRS+rown works for both
#pragma unroll
    for (int i = 0; i < 7; ++i) {
        float v = (noff[i] >= 0) ? nacc[i] : 0.f;
        v += __shfl_xor(v, 1); v += __shfl_xor(v, 2);
        v += __shfl_xor(v, 4); v += __shfl_xor(v, 8);
        int rown = (tid >> 4) + 16 * i;
        if ((tid & 15) == 0 && rown < 98) {
            if (RED) gout[PAIRS + rown] = v;
            else atomicAdd(&gout[PAIRS + rown], v);
        }
    }
}

// ---------------------------------------------------------------------------
// L2: per-batch matching. RED folds the 8-way K-split reduction of the l1
// partial Grams/norms into the d2f build. Selection logic unchanged.
// ---------------------------------------------------------------------------
template<bool RED>
__global__ __launch_bounds__(256) void l2_match(const float* __restrict__ ga,
                                                const float* __restrict__ gb,
                                                float* __restrict__ ws,
                                                const float* __restrict__ l1part)
{
    __shared__ float d2f[PAIRS];
    __shared__ float d2g[PAIRS];
    __shared__ float nAs[49], nBs[49];
    __shared__ float gax[49], gay[49], gbx[49], gby[49];
    __shared__ float mval[4][49];
    __shared__ int   midx[4][49];

    const int tid = threadIdx.x;
    const int batch = blockIdx.x;
    const float* P0 = l1part + (size_t)batch * (RED ? (8 * SLOT) : SLOT);

    auto rd = [&](int off) -> float {
        if (!RED) return P0[off];
        float s = 0.f;
#pragma unroll
        for (int ss = 0; ss < 8; ++ss) s += P0[ss * SLOT + off];
        return s;
    };

    if (tid < 49) nAs[tid] = rd(PAIRS + tid);
    else if (tid >= 64 && tid < 113) nBs[tid - 64] = rd(PAIRS + 49 + (tid - 64));
    if (tid >= 128 && tid < 177) {
        int i = tid - 128;
        gax[i] = ga[batch * 98 + i * 2];
        gay[i] = ga[batch * 98 + i * 2 + 1];
    } else if (tid >= 192 && tid < 241) {
        int i = tid - 192;
        gbx[i] = gb[batch * 98 + i * 2];
        gby[i] = gb[batch * 98 + i * 2 + 1];
    }
    __syncthreads();
    for (int e = tid; e < PAIRS; e += 256) {
        int i = e / 49, j = e - i * 49;
        d2f[e] = nAs[i] + nBs[j] - 2.0f * rd(e);
        float dx = gax[i] - gbx[j], dy = gay[i] - gby[j];
        d2g[e] = dx * dx + dy * dy;
    }
    __syncthreads();
    const int task = tid >> 6, l = tid & 63;
    if (l < 49) {
        float bv = 3.0e38f; int bi = 0;
        if (task == 0) {
            for (int j = 0; j < 49; ++j) { float v = d2f[l * 49 + j]; if (v < bv) { bv = v; bi = j; } }
        } else if (task == 1) {
            for (int i = 0; i < 49; ++i) { float v = d2f[i * 49 + l]; if (v < bv) { bv = v; bi = i; } }
        } else if (task == 2) {
            for (int j = 0; j < 49; ++j) { float v = d2g[l * 49 + j]; if (v < bv) { bv = v; bi = j; } }
        } else {
            for (int i = 0; i < 49; ++i) { float v = d2g[i * 49 + l]; if (v < bv) { bv = v; bi = i; } }
        }
        mval[task][l] = bv; midx[task][l] = bi;
    }
    __syncthreads();
    if (l < 49) {
        float v = mval[task][l];
        int rank = 0;
        for (int k = 0; k < 49; ++k) {
            float u = mval[task][k];
            rank += (u < v) || (u == v && k < l);   // stable: matches lax.top_k ties
        }
        if (task == 0)      { if (rank < 20) atomicAdd(&ws[WS_S1], v); }
        else if (task == 1) { if (rank < 20) atomicAdd(&ws[WS_S2], v); }
        else if (task == 2) { if (rank < 20) atomicAdd(&ws[WS_S3], d2f[l * 49 + midx[2][l]]); }
        else                { if (rank < 4)  atomicAdd(&ws[WS_S4], d2f[midx[3][l] * 49 + l]); }
    }
}

// ---------------------------------------------------------------------------
// GK2: 128x128 Gram of z_a/z_b, K-split 64 chunks of 128 cols + per-column
// sum/sumsq (disjoint -> plain stores). RED: disjoint partials; else atomic.
// ---------------------------------------------------------------------------
template<bool RED>
__global__ __launch_bounds__(256) void gk2_gram(const float* __restrict__ za,
                                                const float* __restrict__ zb,
                                                float* __restrict__ ws,
                                                float* __restrict__ part)
{
    __shared__ float sx[128 * 68];
    const int tid = threadIdx.x;
    const int tensor = blockIdx.x >> 6;
    const int chunk  = blockIdx.x & 63;
    const float* X = (tensor ? zb : za) + chunk * 128;
    const int ty = tid >> 4, tx = tid & 15;
    const int q = tid >> 6, cc = tid & 63;

    float acc[8][8];
#pragma unroll
    for (int r = 0; r < 8; ++r)
#pragma unroll
        for (int c = 0; c < 8; ++c) acc[r][c] = 0.f;
    float colS[2] = {0.f, 0.f}, colQ[2] = {0.f, 0.f};

#pragma unroll
    for (int stage = 0; stage < 2; ++stage) {
        __syncthreads();
        for (int f = tid; f < 128 * 16; f += 256) {
            int row = f >> 4, c4 = f & 15;
            *(float4*)(sx + row * 68 + c4 * 4) =
                *(const float4*)(X + (size_t)row * DIM + stage * 64 + c4 * 4);
        }
        __syncthreads();
        for (int r = 0; r < 32; ++r) {
            float v = sx[(q * 32 + r) * 68 + cc];
            colS[stage] += v; colQ[stage] += v * v;
        }
        for (int k = 0; k < 64; k += 4) {
            float4 a4[8];
#pragma unroll
            for (int r = 0; r < 8; ++r) a4[r] = *(const float4*)(sx + (ty + 16 * r) * 68 + k);
#pragma unroll
            for (int c = 0; c < 8; ++c) {
                float4 b4 = *(const float4*)(sx + (tx + 16 * c) * 68 + k);
#pragma unroll
                for (int r = 0; r < 8; ++r)
                    acc[r][c] += a4[r].x * b4.x + a4[r].y * b4.y + a4[r].z * b4.z + a4[r].w * b4.w;
            }
        }
    }
    __syncthreads();
#pragma unroll
    for (int st = 0; st < 2; ++st) {
        sx[tid] = colS[st];
        sx[256 + tid] = colQ[st];
        __syncthreads();
        if (tid < 64) {
            float s  = sx[tid] + sx[64 + tid] + sx[128 + tid] + sx[192 + tid];
            float qq = sx[256 + tid] + sx[320 + tid] + sx[384 + tid] + sx[448 + tid];
            int col = chunk * 128 + st * 64 + tid;
            float* C = ws + COLS_OFF + tensor * 2 * DIM;
            C[col] = s; C[DIM + col] = qq;
        }
        __syncthreads();
    }
    if (RED) {
        float* P = part + (size_t)blockIdx.x * 16384;
#pragma unroll
        for (int r = 0; r < 8; ++r)
#pragma unroll
            for (int c = 0; c < 8; ++c)
                P[(ty + 16 * r) * 128 + (tx + 16 * c)] = acc[r][c];
    } else {
        float* G = ws + (tensor ? GRAMB_OFF : GRAMA_OFF);
#pragma unroll
        for (int r = 0; r < 8; ++r)
#pragma unroll
            for (int c = 0; c < 8; ++c)
                atomicAdd(&G[(ty + 16 * r) * 128 + (tx + 16 * c)], acc[r][c]);
    }
}

__global__ __launch_bounds__(256) void gk2_reduce(float* __restrict__ ws)
{
    const int g = blockIdx.x * 256 + threadIdx.x;   // 0..32767
    const int tensor = g >> 14;
    const int e = g & 16383;
    const float* P = ws + GK2PART_OFF + (size_t)tensor * 64 * 16384;
    float s = 0.f;
    for (int c = 0; c < 64; ++c) s += P[(size_t)c * 16384 + e];
    ws[(tensor ? GRAMB_OFF : GRAMA_OFF) + e] = s;
}

// ---------------------------------------------------------------------------
// GK1m: global MSE. GK1b: per-column std/relu/diag -> scalars.
// ---------------------------------------------------------------------------
__global__ __launch_bounds__(256) void gk1_mse(const float* __restrict__ za,
                                               const float* __restrict__ zb,
                                               float* __restrict__ ws)
{
    const size_t i0 = ((size_t)blockIdx.x * 256 + threadIdx.x) * 4;
    float ms = 0.f;
#pragma unroll
    for (int it = 0; it < 4; ++it) {
        size_t idx = i0 + (size_t)it * 262144;
        float4 a = *(const float4*)(za + idx);
        float4 b = *(const float4*)(zb + idx);
        float dx = a.x - b.x, dy = a.y - b.y, dz = a.z - b.z, dw = a.w - b.w;
        ms += dx * dx + dy * dy + dz * dz + dw * dw;
    }
    for (int o = 32; o; o >>= 1) ms += __shfl_xor(ms, o);
    if ((threadIdx.x & 63) == 0) atomicAdd(&ws[WS_MSE], ms);
}

__global__ __launch_bounds__(256) void gk1b(float* __restrict__ ws)
{
    const int col = blockIdx.x * 256 + threadIdx.x;
    float sa = ws[COLS_OFF + col];
    float qa = ws[COLS_OFF + DIM + col];
    float sb = ws[COLS_OFF + 2 * DIM + col];
    float qb = ws[COLS_OFF + 3 * DIM + col];
    float sA = qa - sa * sa * (1.0f / BATCH);
    float sB = qb - sb * sb * (1.0f / BATCH);
    float rA = fmaxf(0.f, 1.f - sqrtf(sA * (1.0f / (BATCH - 1)) + 1e-4f));
    float rB = fmaxf(0.f, 1.f - sqrtf(sB * (1.0f / (BATCH - 1)) + 1e-4f));
    float dA = sA * sA, dB = sB * sB;
    for (int o = 32; o; o >>= 1) {
        rA += __shfl_xor(rA, o);
        rB += __shfl_xor(rB, o);
        dA += __shfl_xor(dA, o);
        dB += __shfl_xor(dB, o);
    }
    if ((threadIdx.x & 63) == 0) {
        atomicAdd(&ws[WS_VARA],  rA);
        atomicAdd(&ws[WS_VARB],  rB);
        atomicAdd(&ws[WS_DIAGA], dA);
        atomicAdd(&ws[WS_DIAGB], dB);
    }
}

// ---------------------------------------------------------------------------
// GK3: ||K||_F^2 from the Gram. K = G - (r_i+r_j)/n + S/n^2.
// ---------------------------------------------------------------------------
__global__ __launch_bounds__(256) void gk3_cov(float* __restrict__ ws)
{
    __shared__ float r[128];
    __shared__ float sS;
    __shared__ float wrd[4];
    const int tid = threadIdx.x;
    const float* G = ws + (blockIdx.x ? GRAMB_OFF : GRAMA_OFF);
    if (tid < 128) {
        float s0 = 0.f, s1 = 0.f, s2 = 0.f, s3 = 0.f;
        for (int k = 0; k < 128; k += 4) {
            s0 += G[(k + 0) * 128 + tid];
            s1 += G[(k + 1) * 128 + tid];
            s2 += G[(k + 2) * 128 + tid];
            s3 += G[(k + 3) * 128 + tid];
        }
        r[tid] = (s0 + s1) + (s2 + s3);
    }
    __syncthreads();
    if (tid < 64) {
        float t = r[tid] + r[tid + 64];
        for (int o = 32; o; o >>= 1) t += __shfl_xor(t, o);
        if (tid == 0) sS = t;
    }
    __syncthreads();
    const float S = sS;
    float sk = 0.f;
    for (int e = tid; e < 16384; e += 256) {
        float K = G[e] - (r[e >> 7] + r[e & 127]) * (1.0f / 128.0f) + S * (1.0f / 16384.0f);
        sk += K * K;
    }
    for (int o = 32; o; o >>= 1) sk += __shfl_xor(sk, o);
    if ((tid & 63) == 0) wrd[tid >> 6] = sk;
    __syncthreads();
    if (tid == 0)
        ws[blockIdx.x ? WS_SK2B : WS_SK2A] = wrd[0] + wrd[1] + wrd[2] + wrd[3];
}

// ---------------------------------------------------------------------------
// GK4: final scalar assembly.
// ---------------------------------------------------------------------------
__global__ void gk4_final(const float* __restrict__ ws, float* __restrict__ out)
{
    if (threadIdx.x == 0) {
        float inv_g = ws[WS_MSE] * (1.0f / ((float)BATCH * (float)DIM));
        float varl  = 0.5f * (ws[WS_VARA] + ws[WS_VARB]) * (1.0f / (float)DIM);
        float cov   = (ws[WS_SK2A] - ws[WS_DIAGA] + ws[WS_SK2B] - ws[WS_DIAGB])
                      * (1.0f / (127.0f * 127.0f * (float)DIM));
        float gl = 25.0f * inv_g + 25.0f * varl + cov;
        float m20 = (float)BATCH * 20.0f * (float)DIM;
        float m4  = (float)BATCH * 4.0f  * (float)DIM;
        float invl = 0.5f * (ws[WS_S1] + ws[WS_S2] + ws[WS_S3]) / m20
                   + 0.5f * ws[WS_S4] / m4;
        out[0] = 0.25f * gl + 0.75f * (25.0f * invl);
    }
}

extern "C" void kernel_launch(void* const* d_in, const int* in_sizes, int n_in,
                              void* d_out, int out_size, void* d_ws, size_t ws_size,
                              hipStream_t stream)
{
    (void)in_sizes; (void)n_in; (void)out_size;
    const float* z_a = (const float*)d_in[0];
    const float* z_b = (const float*)d_in[1];
    const float* zla = (const float*)d_in[2];
    const float* zlb = (const float*)d_in[3];
    const float* ga  = (const float*)d_in[4];
    const float* gb  = (const float*)d_in[5];
    float* ws  = (float*)d_ws;
    float* out = (float*)d_out;

    const bool big = ws_size >= (size_t)WS_NEED_FLOATS * sizeof(float);

    if (big) {
        hipMemsetAsync(d_ws, 0, 16 * sizeof(float), stream);
        l1_gram<true><<<BATCH * 8, 256, 0, stream>>>(zla, zlb, ws + L1PART_BIG);
        gk2_gram<true><<<128, 256, 0, stream>>>(z_a, z_b, ws, ws + GK2PART_OFF);
        gk2_reduce<<<128, 256, 0, stream>>>(ws);
        gk1_mse<<<256, 256, 0, stream>>>(z_a, z_b, ws);
        gk1b<<<DIM / 256, 256, 0, stream>>>(ws);
        l2_match<true><<<BATCH, 256, 0, stream>>>(ga, gb, ws, ws + L1PART_BIG);
        gk3_cov<<<2, 256, 0, stream>>>(ws);
        gk4_final<<<1, 64, 0, stream>>>(ws, out);
    } else {
        hipMemsetAsync(d_ws, 0, (size_t)(L1PART_SMALL + BATCH * SLOT) * sizeof(float), stream);
        l1_gram<false><<<BATCH * 8, 256, 0, stream>>>(zla, zlb, ws + L1PART_SMALL);
        gk2_gram<false><<<128, 256, 0, stream>>>(z_a, z_b, ws, ws);
        gk1_mse<<<256, 256, 0, stream>>>(z_a, z_b, ws);
        gk1b<<<DIM / 256, 256, 0, stream>>>(ws);
        l2_match<false><<<BATCH, 256, 0, stream>>>(ga, gb, ws, ws + L1PART_SMALL);
        gk3_cov<<<2, 256, 0, stream>>>(ws);
        gk4_final<<<1, 64, 0, stream>>>(ws, out);
    }
}

// Round 8
// 174.009 us; speedup vs baseline: 1.4009x; 1.0586x over previous
//
#include <hip/hip_runtime.h>
#include <math.h>

#define BATCH 128
#define DIM   8192
#define HW    49
#define PAIRS 2401            // 49*49
#define SLOT  2512            // per-partial slot: 2401 G + 49 nA + 49 nB + pad

// ws float offsets
#define WS_MSE    0
#define WS_VARA   1
#define WS_VARB   2
#define WS_DIAGA  3
#define WS_DIAGB  4
#define WS_S1     5
#define WS_S2     6
#define WS_S3     7
#define WS_S4     8
#define WS_SK2A   9
#define WS_SK2B   10
#define COLS_OFF    16                         // sa,qa,sb,qb: 4*DIM
#define GRAMA_OFF   32784
#define GRAMB_OFF   49168
#define GK2PART_OFF 65552                      // 128 blocks * 16384
#define L1PART_BIG  2162704                    // 512 blocks * SLOT
#define WS_NEED_FLOATS (L1PART_BIG + 512 * SLOT)    // ~13.8 MB
#define L1PART_SMALL 65552                     // fallback: 128 batch slots (atomic)

typedef __attribute__((ext_vector_type(8))) short bf16x8;
typedef __attribute__((ext_vector_type(4))) float f32x4;

__device__ __forceinline__ unsigned cvtpk(float lo, float hi) {
    unsigned r;
    asm("v_cvt_pk_bf16_f32 %0, %1, %2" : "=v"(r) : "v"(lo), "v"(hi));
    return r;
}
__device__ __forceinline__ bf16x8 cvt8(f32x4 a, f32x4 b) {
    union { unsigned u[4]; bf16x8 v; } r;
    r.u[0] = cvtpk(a.x, a.y); r.u[1] = cvtpk(a.z, a.w);
    r.u[2] = cvtpk(b.x, b.y); r.u[3] = cvtpk(b.z, b.w);
    return r.v;
}
__device__ __forceinline__ f32x4 ld4(const unsigned char* p) {
    return *(const f32x4*)p;
}
// DMA global->LDS, 16B/lane, lane i -> ldsbase + i*16 (linear dest; per-lane src ok)
__device__ __forceinline__ void gload16(const float* g, unsigned char* l) {
    __builtin_amdgcn_global_load_lds(
        (const __attribute__((address_space(1))) void*)g,
        (__attribute__((address_space(3))) void*)l, 16, 0, 0);
}

// ---------------------------------------------------------------------------
// L1: per-batch padded 64x64 Gram of 49x8192 features via bf16 MFMA.
// grid = 128 batches * 4 K-splits (K=2048) = 512 blocks, 512 thr (8 waves),
// 1 block/CU (98KB LDS). DRAM-granularity design: ONE DMA instruction = ONE
// row-touch of 1KB CONTIGUOUS (64 lanes x 16B, BK=256 fp32). 8 stages of
// {issue 98 DMA -> barrier (vmcnt drain; ~98KB in flight keeps queues full)
// -> MFMA + norms from LDS -> barrier}. Global source slots XOR-permuted
// (lane ^ (row&15), involution) so fragment ds_read_b128s are 2-way max;
// norm reads are linear (sum is permutation-invariant).
// Wave w owns C-tile rows [wr*32,+32) cols [wc*16,+16) (wr=w>>2, wc=w&3):
// 2 A-frags + 1 B-frag, 2 MFMA per K-step, 16 per stage. Disjoint stores.
// ---------------------------------------------------------------------------
template<bool RED>
__global__ __launch_bounds__(512) void l1_gram(const float* __restrict__ za,
                                               const float* __restrict__ zb,
                                               float* __restrict__ l1part)
{
    __shared__ __align__(16) unsigned char buf[98 * 1024];   // 98 rows x 1KB fp32

    const int tid  = threadIdx.x;
    const int wv   = tid >> 6;          // 0..7
    const int lane = tid & 63;
    const int fr = lane & 15, kg = lane >> 4;
    const int batch = blockIdx.x >> 2;
    const int ks    = blockIdx.x & 3;   // K-split of 2048 floats

    const float* Az = za + (size_t)batch * HW * DIM + (size_t)ks * 2048;
    const float* Bz = zb + (size_t)batch * HW * DIM + (size_t)ks * 2048;

    // ---- DMA descriptors: wave w stages rows j = w + 8i (<= 13 rows/wave)
    const float* gp[13];
    int jb[13];
#pragma unroll
    for (int i = 0; i < 13; ++i) {
        int j = wv + 8 * i;
        if (j < 98) {
            const float* rbase = (j < 49) ? (Az + (size_t)j * DIM)
                                          : (Bz + (size_t)(j - 49) * DIM);
            gp[i] = rbase + ((lane ^ (j & 15)) << 2);   // permuted 16B slot
            jb[i] = j << 10;
        } else { gp[i] = Az; jb[i] = -1; }
    }

    // ---- fragment bases: A rows (2 per wave), B row (1 per wave)
    const int wr = wv >> 2, wc = wv & 3;
    int ar0 = wr * 32 + fr;           if (ar0 > 48) ar0 = 48;   // never clamps (<=47)
    int ar1 = wr * 32 + 16 + fr;      if (ar1 > 48) ar1 = 48;   // pad rows clamp
    int bc  = wc * 16 + fr;           if (bc  > 48) bc  = 48;
    const int br  = 49 + bc;
    const int aw0 = ar0 << 10, ax0 = ar0 & 15;
    const int aw1 = ar1 << 10, ax1 = ar1 & 15;
    const int bw  = br  << 10, bx  = br  & 15;
    const int kg2 = kg * 2;

    // ---- norm descriptors: thread owns rows (tid>>4)+32i, slots (tid&15)+16q
    int nr[4]; float nacc[4];
    const int nslot = (tid & 15) << 4;
#pragma unroll
    for (int i = 0; i < 4; ++i) {
        int r = (tid >> 4) + 32 * i;
        nr[i] = (r < 98) ? (r << 10) : -1;
        nacc[i] = 0.f;
    }

    f32x4 acc0 = {0.f, 0.f, 0.f, 0.f}, acc1 = {0.f, 0.f, 0.f, 0.f};

#pragma unroll 1
    for (int s = 0; s < 8; ++s) {
        // issue 98 x 1KB-contiguous DMA (queues full while we wait)
#pragma unroll
        for (int i = 0; i < 13; ++i)
            if (jb[i] >= 0) gload16(gp[i] + (size_t)s * 256, buf + jb[i]);
        __syncthreads();                 // vmcnt drains: stage resident
        // compute: 8 K-steps of 32
#pragma unroll
        for (int kk = 0; kk < 8; ++kk) {
            const int s0 = kk * 8 + kg2;
            bf16x8 a0 = cvt8(ld4(buf + aw0 + (((s0) ^ ax0) << 4)),
                             ld4(buf + aw0 + (((s0 + 1) ^ ax0) << 4)));
            bf16x8 a1 = cvt8(ld4(buf + aw1 + (((s0) ^ ax1) << 4)),
                             ld4(buf + aw1 + (((s0 + 1) ^ ax1) << 4)));
            bf16x8 b0 = cvt8(ld4(buf + bw + (((s0) ^ bx) << 4)),
                             ld4(buf + bw + (((s0 + 1) ^ bx) << 4)));
            acc0 = __builtin_amdgcn_mfma_f32_16x16x32_bf16(a0, b0, acc0, 0, 0, 0);
            acc1 = __builtin_amdgcn_mfma_f32_16x16x32_bf16(a1, b0, acc1, 0, 0, 0);
        }
        // norms (linear LDS reads; permutation-invariant)
#pragma unroll
        for (int i = 0; i < 4; ++i)
            if (nr[i] >= 0) {
#pragma unroll
                for (int q = 0; q < 4; ++q) {
                    f32x4 v = ld4(buf + nr[i] + nslot + q * 256);
                    nacc[i] += v.x * v.x + v.y * v.y + v.z * v.z + v.w * v.w;
                }
            }
        __syncthreads();                 // reads done before next overwrite
    }

    // ---- epilogue: disjoint quadrant stores (RED) / atomics (fallback)
    float* gout = l1part + (size_t)(RED ? blockIdx.x : batch) * SLOT;
    const int gc = wc * 16 + fr;
#pragma unroll
    for (int rr = 0; rr < 4; ++rr) {
        int gr0 = wr * 32 + kg * 4 + rr;
        int gr1 = gr0 + 16;
        if (gc < HW) {
            if (gr0 < HW) {
                if (RED) gout[gr0 * HW + gc] = acc0[rr];
                else atomicAdd(&gout[gr0 * HW + gc], acc0[rr]);
            }
            if (gr1 < HW) {
                if (RED) gout[gr1 * HW + gc] = acc1[rr];
                else atomicAdd(&gout[gr1 * HW + gc], acc1[rr]);
            }
        }
    }
    // norms: 16 consecutive lanes per row -> shfl tree over lane&15
#pragma unroll
    for (int i = 0; i < 4; ++i) {
        float v = (nr[i] >= 0) ? nacc[i] : 0.f;
        v += __shfl_xor(v, 1); v += __shfl_xor(v, 2);
        v += __shfl_xor(v, 4); v += __shfl_xor(v, 8);
        int r = (tid >> 4) + 32 * i;
        if ((tid & 15) == 0 && r < 98) {
            if (RED) gout[PAIRS + r] = v;
            else atomicAdd(&gout[PAIRS + r], v);
        }
    }
}

// ---------------------------------------------------------------------------
// L2: per-batch matching. RED folds the 4-way K-split reduction of the l1
// partial Grams/norms into the d2f build. Selection logic unchanged.
// ---------------------------------------------------------------------------
template<bool RED>
__global__ __launch_bounds__(256) void l2_match(const float* __restrict__ ga,
                                                const float* __restrict__ gb,
                                                float* __restrict__ ws,
                                                const float* __restrict__ l1part)
{
    __shared__ float d2f[PAIRS];
    __shared__ float d2g[PAIRS];
    __shared__ float nAs[49], nBs[49];
    __shared__ float gax[49], gay[49], gbx[49], gby[49];
    __shared__ float mval[4][49];
    __shared__ int   midx[4][49];

    const int tid = threadIdx.x;
    const int batch = blockIdx.x;
    const float* P0 = l1part + (size_t)batch * (RED ? (4 * SLOT) : SLOT);

    auto rd = [&](int off) -> float {
        if (!RED) return P0[off];
        float s = 0.f;
#pragma unroll
        for (int ss = 0; ss < 4; ++ss) s += P0[ss * SLOT + off];
        return s;
    };

    if (tid < 49) nAs[tid] = rd(PAIRS + tid);
    else if (tid >= 64 && tid < 113) nBs[tid - 64] = rd(PAIRS + 49 + (tid - 64));
    if (tid >= 128 && tid < 177) {
        int i = tid - 128;
        gax[i] = ga[batch * 98 + i * 2];
        gay[i] = ga[batch * 98 + i * 2 + 1];
    } else if (tid >= 192 && tid < 241) {
        int i = tid - 192;
        gbx[i] = gb[batch * 98 + i * 2];
        gby[i] = gb[batch * 98 + i * 2 + 1];
    }
    __syncthreads();
    for (int e = tid; e < PAIRS; e += 256) {
        int i = e / 49, j = e - i * 49;
        d2f[e] = nAs[i] + nBs[j] - 2.0f * rd(e);
        float dx = gax[i] - gbx[j], dy = gay[i] - gby[j];
        d2g[e] = dx * dx + dy * dy;
    }
    __syncthreads();
    const int task = tid >> 6, l = tid & 63;
    if (l < 49) {
        float bv = 3.0e38f; int bi = 0;
        if (task == 0) {
            for (int j = 0; j < 49; ++j) { float v = d2f[l * 49 + j]; if (v < bv) { bv = v; bi = j; } }
        } else if (task == 1) {
            for (int i = 0; i < 49; ++i) { float v = d2f[i * 49 + l]; if (v < bv) { bv = v; bi = i; } }
        } else if (task == 2) {
            for (int j = 0; j < 49; ++j) { float v = d2g[l * 49 + j]; if (v < bv) { bv = v; bi = j; } }
        } else {
            for (int i = 0; i < 49; ++i) { float v = d2g[i * 49 + l]; if (v < bv) { bv = v; bi = i; } }
        }
        mval[task][l] = bv; midx[task][l] = bi;
    }
    __syncthreads();
    if (l < 49) {
        float v = mval[task][l];
        int rank = 0;
        for (int k = 0; k < 49; ++k) {
            float u = mval[task][k];
            rank += (u < v) || (u == v && k < l);   // stable: matches lax.top_k ties
        }
        if (task == 0)      { if (rank < 20) atomicAdd(&ws[WS_S1], v); }
        else if (task == 1) { if (rank < 20) atomicAdd(&ws[WS_S2], v); }
        else if (task == 2) { if (rank < 20) atomicAdd(&ws[WS_S3], d2f[l * 49 + midx[2][l]]); }
        else                { if (rank < 4)  atomicAdd(&ws[WS_S4], d2f[midx[3][l] * 49 + l]); }
    }
}

// ---------------------------------------------------------------------------
// GK2: 128x128 Gram of z_a/z_b, K-split 64 chunks of 128 cols + per-column
// sum/sumsq (disjoint -> plain stores). RED: disjoint partials; else atomic.
// ---------------------------------------------------------------------------
template<bool RED>
__global__ __launch_bounds__(256) void gk2_gram(const float* __restrict__ za,
                                                const float* __restrict__ zb,
                                                float* __restrict__ ws,
                                                float* __restrict__ part)
{
    __shared__ float sx[128 * 68];
    const int tid = threadIdx.x;
    const int tensor = blockIdx.x >> 6;
    const int chunk  = blockIdx.x & 63;
    const float* X = (tensor ? zb : za) + chunk * 128;
    const int ty = tid >> 4, tx = tid & 15;
    const int q = tid >> 6, cc = tid & 63;

    float acc[8][8];
#pragma unroll
    for (int r = 0; r < 8; ++r)
#pragma unroll
        for (int c = 0; c < 8; ++c) acc[r][c] = 0.f;
    float colS[2] = {0.f, 0.f}, colQ[2] = {0.f, 0.f};

#pragma unroll
    for (int stage = 0; stage < 2; ++stage) {
        __syncthreads();
        for (int f = tid; f < 128 * 16; f += 256) {
            int row = f >> 4, c4 = f & 15;
            *(float4*)(sx + row * 68 + c4 * 4) =
                *(const float4*)(X + (size_t)row * DIM + stage * 64 + c4 * 4);
        }
        __syncthreads();
        for (int r = 0; r < 32; ++r) {
            float v = sx[(q * 32 + r) * 68 + cc];
            colS[stage] += v; colQ[stage] += v * v;
        }
        for (int k = 0; k < 64; k += 4) {
            float4 a4[8];
#pragma unroll
            for (int r = 0; r < 8; ++r) a4[r] = *(const float4*)(sx + (ty + 16 * r) * 68 + k);
#pragma unroll
            for (int c = 0; c < 8; ++c) {
                float4 b4 = *(const float4*)(sx + (tx + 16 * c) * 68 + k);
#pragma unroll
                for (int r = 0; r < 8; ++r)
                    acc[r][c] += a4[r].x * b4.x + a4[r].y * b4.y + a4[r].z * b4.z + a4[r].w * b4.w;
            }
        }
    }
    __syncthreads();
#pragma unroll
    for (int st = 0; st < 2; ++st) {
        sx[tid] = colS[st];
        sx[256 + tid] = colQ[st];
        __syncthreads();
        if (tid < 64) {
            float s  = sx[tid] + sx[64 + tid] + sx[128 + tid] + sx[192 + tid];
            float qq = sx[256 + tid] + sx[320 + tid] + sx[384 + tid] + sx[448 + tid];
            int col = chunk * 128 + st * 64 + tid;
            float* C = ws + COLS_OFF + tensor * 2 * DIM;
            C[col] = s; C[DIM + col] = qq;
        }
        __syncthreads();
    }
    if (RED) {
        float* P = part + (size_t)blockIdx.x * 16384;
#pragma unroll
        for (int r = 0; r < 8; ++r)
#pragma unroll
            for (int c = 0; c < 8; ++c)
                P[(ty + 16 * r) * 128 + (tx + 16 * c)] = acc[r][c];
    } else {
        float* G = ws + (tensor ? GRAMB_OFF : GRAMA_OFF);
#pragma unroll
        for (int r = 0; r < 8; ++r)
#pragma unroll
            for (int c = 0; c < 8; ++c)
                atomicAdd(&G[(ty + 16 * r) * 128 + (tx + 16 * c)], acc[r][c]);
    }
}

__global__ __launch_bounds__(256) void gk2_reduce(float* __restrict__ ws)
{
    const int g = blockIdx.x * 256 + threadIdx.x;   // 0..32767
    const int tensor = g >> 14;
    const int e = g & 16383;
    const float* P = ws + GK2PART_OFF + (size_t)tensor * 64 * 16384;
    float s = 0.f;
    for (int c = 0; c < 64; ++c) s += P[(size_t)c * 16384 + e];
    ws[(tensor ? GRAMB_OFF : GRAMA_OFF) + e] = s;
}

// ---------------------------------------------------------------------------
// GK1m: global MSE. GK1b: per-column std/relu/diag -> scalars.
// ---------------------------------------------------------------------------
__global__ __launch_bounds__(256) void gk1_mse(const float* __restrict__ za,
                                               const float* __restrict__ zb,
                                               float* __restrict__ ws)
{
    const size_t i0 = ((size_t)blockIdx.x * 256 + threadIdx.x) * 4;
    float ms = 0.f;
#pragma unroll
    for (int it = 0; it < 4; ++it) {
        size_t idx = i0 + (size_t)it * 262144;
        float4 a = *(const float4*)(za + idx);
        float4 b = *(const float4*)(zb + idx);
        float dx = a.x - b.x, dy = a.y - b.y, dz = a.z - b.z, dw = a.w - b.w;
        ms += dx * dx + dy * dy + dz * dz + dw * dw;
    }
    for (int o = 32; o; o >>= 1) ms += __shfl_xor(ms, o);
    if ((threadIdx.x & 63) == 0) atomicAdd(&ws[WS_MSE], ms);
}

__global__ __launch_bounds__(256) void gk1b(float* __restrict__ ws)
{
    const int col = blockIdx.x * 256 + threadIdx.x;
    float sa = ws[COLS_OFF + col];
    float qa = ws[COLS_OFF + DIM + col];
    float sb = ws[COLS_OFF + 2 * DIM + col];
    float qb = ws[COLS_OFF + 3 * DIM + col];
    float sA = qa - sa * sa * (1.0f / BATCH);
    float sB = qb - sb * sb * (1.0f / BATCH);
    float rA = fmaxf(0.f, 1.f - sqrtf(sA * (1.0f / (BATCH - 1)) + 1e-4f));
    float rB = fmaxf(0.f, 1.f - sqrtf(sB * (1.0f / (BATCH - 1)) + 1e-4f));
    float dA = sA * sA, dB = sB * sB;
    for (int o = 32; o; o >>= 1) {
        rA += __shfl_xor(rA, o);
        rB += __shfl_xor(rB, o);
        dA += __shfl_xor(dA, o);
        dB += __shfl_xor(dB, o);
    }
    if ((threadIdx.x & 63) == 0) {
        atomicAdd(&ws[WS_VARA],  rA);
        atomicAdd(&ws[WS_VARB],  rB);
        atomicAdd(&ws[WS_DIAGA], dA);
        atomicAdd(&ws[WS_DIAGB], dB);
    }
}

// ---------------------------------------------------------------------------
// GK3: ||K||_F^2 from the Gram. K = G - (r_i+r_j)/n + S/n^2.
// ---------------------------------------------------------------------------
__global__ __launch_bounds__(256) void gk3_cov(float* __restrict__ ws)
{
    __shared__ float r[128];
    __shared__ float sS;
    __shared__ float wrd[4];
    const int tid = threadIdx.x;
    const float* G = ws + (blockIdx.x ? GRAMB_OFF : GRAMA_OFF);
    if (tid < 128) {
        float s0 = 0.f, s1 = 0.f, s2 = 0.f, s3 = 0.f;
        for (int k = 0; k < 128; k += 4) {
            s0 += G[(k + 0) * 128 + tid];
            s1 += G[(k + 1) * 128 + tid];
            s2 += G[(k + 2) * 128 + tid];
            s3 += G[(k + 3) * 128 + tid];
        }
        r[tid] = (s0 + s1) + (s2 + s3);
    }
    __syncthreads();
    if (tid < 64) {
        float t = r[tid] + r[tid + 64];
        for (int o = 32; o; o >>= 1) t += __shfl_xor(t, o);
        if (tid == 0) sS = t;
    }
    __syncthreads();
    const float S = sS;
    float sk = 0.f;
    for (int e = tid; e < 16384; e += 256) {
        float K = G[e] - (r[e >> 7] + r[e & 127]) * (1.0f / 128.0f) + S * (1.0f / 16384.0f);
        sk += K * K;
    }
    for (int o = 32; o; o >>= 1) sk += __shfl_xor(sk, o);
    if ((tid & 63) == 0) wrd[tid >> 6] = sk;
    __syncthreads();
    if (tid == 0)
        ws[blockIdx.x ? WS_SK2B : WS_SK2A] = wrd[0] + wrd[1] + wrd[2] + wrd[3];
}

// ---------------------------------------------------------------------------
// GK4: final scalar assembly.
// ---------------------------------------------------------------------------
__global__ void gk4_final(const float* __restrict__ ws, float* __restrict__ out)
{
    if (threadIdx.x == 0) {
        float inv_g = ws[WS_MSE] * (1.0f / ((float)BATCH * (float)DIM));
        float varl  = 0.5f * (ws[WS_VARA] + ws[WS_VARB]) * (1.0f / (float)DIM);
        float cov   = (ws[WS_SK2A] - ws[WS_DIAGA] + ws[WS_SK2B] - ws[WS_DIAGB])
                      * (1.0f / (127.0f * 127.0f * (float)DIM));
        float gl = 25.0f * inv_g + 25.0f * varl + cov;
        float m20 = (float)BATCH * 20.0f * (float)DIM;
        float m4  = (float)BATCH * 4.0f  * (float)DIM;
        float invl = 0.5f * (ws[WS_S1] + ws[WS_S2] + ws[WS_S3]) / m20
                   + 0.5f * ws[WS_S4] / m4;
        out[0] = 0.25f * gl + 0.75f * (25.0f * invl);
    }
}

extern "C" void kernel_launch(void* const* d_in, const int* in_sizes, int n_in,
                              void* d_out, int out_size, void* d_ws, size_t ws_size,
                              hipStream_t stream)
{
    (void)in_sizes; (void)n_in; (void)out_size;
    const float* z_a = (const float*)d_in[0];
    const float* z_b = (const float*)d_in[1];
    const float* zla = (const float*)d_in[2];
    const float* zlb = (const float*)d_in[3];
    const float* ga  = (const float*)d_in[4];
    const float* gb  = (const float*)d_in[5];
    float* ws  = (float*)d_ws;
    float* out = (float*)d_out;

    const bool big = ws_size >= (size_t)WS_NEED_FLOATS * sizeof(float);

    if (big) {
        hipMemsetAsync(d_ws, 0, 16 * sizeof(float), stream);
        l1_gram<true><<<BATCH * 4, 512, 0, stream>>>(zla, zlb, ws + L1PART_BIG);
        gk2_gram<true><<<128, 256, 0, stream>>>(z_a, z_b, ws, ws + GK2PART_OFF);
        gk2_reduce<<<128, 256, 0, stream>>>(ws);
        gk1_mse<<<256, 256, 0, stream>>>(z_a, z_b, ws);
        gk1b<<<DIM / 256, 256, 0, stream>>>(ws);
        l2_match<true><<<BATCH, 256, 0, stream>>>(ga, gb, ws, ws + L1PART_BIG);
        gk3_cov<<<2, 256, 0, stream>>>(ws);
        gk4_final<<<1, 64, 0, stream>>>(ws, out);
    } else {
        hipMemsetAsync(d_ws, 0, (size_t)(L1PART_SMALL + BATCH * SLOT) * sizeof(float), stream);
        l1_gram<false><<<BATCH * 4, 512, 0, stream>>>(zla, zlb, ws + L1PART_SMALL);
        gk2_gram<false><<<128, 256, 0, stream>>>(z_a, z_b, ws, ws);
        gk1_mse<<<256, 256, 0, stream>>>(z_a, z_b, ws);
        gk1b<<<DIM / 256, 256, 0, stream>>>(ws);
        l2_match<false><<<BATCH, 256, 0, stream>>>(ga, gb, ws, ws + L1PART_SMALL);
        gk3_cov<<<2, 256, 0, stream>>>(ws);
        gk4_final<<<1, 64, 0, stream>>>(ws, out);
    }
}

// Round 9
// 143.052 us; speedup vs baseline: 1.7041x; 1.2164x over previous
//
#include <hip/hip_runtime.h>
#include <math.h>

#define BATCH 128
#define DIM   8192
#define HW    49
#define PAIRS 2401            // 49*49
#define SLOT  2512            // per-partial slot: 2401 G + 49 nA + 49 nB + pad

// ws float offsets
#define WS_MSE    0
#define WS_VARA   1
#define WS_VARB   2
#define WS_DIAGA  3
#define WS_DIAGB  4
#define WS_S1     5
#define WS_S2     6
#define WS_S3     7
#define WS_S4     8
#define WS_SK2A   9
#define WS_SK2B   10
#define COLS_OFF    16                         // saA,qaA,saB,qbB: 4*DIM
#define GRAMA_OFF   32784
#define GRAMB_OFF   49168
#define GK2PART_OFF 65552                      // 64 chunks * 32768 (A then B)
#define L1PART_BIG  2162704                    // 256 blocks * SLOT
#define WS_NEED_FLOATS (L1PART_BIG + 256 * SLOT)    // ~11.2 MB
#define L1PART_SMALL 65552                     // fallback: 128 batch slots (atomic)

typedef __attribute__((ext_vector_type(8))) short bf16x8;
typedef __attribute__((ext_vector_type(4))) float f32x4;

__device__ __forceinline__ unsigned cvtpk(float lo, float hi) {
    unsigned r;
    asm("v_cvt_pk_bf16_f32 %0, %1, %2" : "=v"(r) : "v"(lo), "v"(hi));
    return r;
}
__device__ __forceinline__ bf16x8 cvt8(f32x4 a, f32x4 b) {
    union { unsigned u[4]; bf16x8 v; } r;
    r.u[0] = cvtpk(a.x, a.y); r.u[1] = cvtpk(a.z, a.w);
    r.u[2] = cvtpk(b.x, b.y); r.u[3] = cvtpk(b.z, b.w);
    return r.v;
}
__device__ __forceinline__ f32x4 ld4(const unsigned char* p) {
    return *(const f32x4*)p;
}
// DMA global->LDS, 16B/lane, lane i -> ldsbase + i*16. No VGPR dest => cannot
// be sunk/serialized by the register allocator (rounds 3-5 failure mode).
__device__ __forceinline__ void gload16(const float* g, unsigned char* l) {
    __builtin_amdgcn_global_load_lds(
        (const __attribute__((address_space(1))) void*)g,
        (__attribute__((address_space(3))) void*)l, 16, 0, 0);
}

// ---------------------------------------------------------------------------
// UBER kernel, 512 threads:
//  blocks 0..255  : L1 role — per-batch padded 64x64 Gram of 49x8192 features
//    via bf16 MFMA. 128 batches x 2 K-halves (K=4096, 32 stages of BK=128).
//    TRUE double buffer 2x49KB: {issue DMA(s+1)->buf[p^1]; compute buf[p];
//    __syncthreads (drains prefetch vmcnt + lgkm); p^=1} — fill(s+1) overlaps
//    compute(s). Row norms come from MFMA diagonals (mfma(a,a), mfma(b,b)) —
//    no LDS norm reads. Global source slots XOR-permuted (slot ^ (row&31),
//    involution) so fragment ds_read_b128s are low-conflict; DMA LDS dest
//    linear (1 instr = 2 rows x 512B).
//  blocks 256..319: GK2 role — 128x128 Grams of BOTH z_a,z_b (chunk of 128
//    cols), per-column sum/sumsq for both, and the global MSE (fused).
// ---------------------------------------------------------------------------
template<bool RED>
__global__ __launch_bounds__(512) void uber(const float* __restrict__ za_l,
                                            const float* __restrict__ zb_l,
                                            const float* __restrict__ z_a,
                                            const float* __restrict__ z_b,
                                            float* __restrict__ ws,
                                            float* __restrict__ l1part)
{
    __shared__ __align__(16) unsigned char shm[100352];
    const int tid = threadIdx.x;

    if (blockIdx.x < 256) {
        // ================= L1 role =================
        unsigned char* buf0 = shm;
        unsigned char* buf1 = shm + 50176;
        const int wv = tid >> 6, lane = tid & 63;
        const int fr = lane & 15, kg = lane >> 4;
        const int batch = blockIdx.x >> 1;
        const int kh    = blockIdx.x & 1;
        const float* Az = za_l + (size_t)batch * HW * DIM + (size_t)kh * 4096;
        const float* Bz = zb_l + (size_t)batch * HW * DIM + (size_t)kh * 4096;

        // DMA descriptors: pair j = wv + 8i covers rows 2j (lanes 0-31) and
        // 2j+1 (lanes 32-63); LDS dest linear at j*1024 + lane*16.
        const float* gp[7];
        int jb[7];
        const int half = lane >> 5, l5 = lane & 31;
#pragma unroll
        for (int i = 0; i < 7; ++i) {
            int j = wv + 8 * i;
            gp[i] = Az; jb[i] = -1;
            if (j < 49) {
                int row = 2 * j + half;
                const float* rbase = (row < 49) ? (Az + (size_t)row * DIM)
                                                : (Bz + (size_t)(row - 49) * DIM);
                gp[i] = rbase + ((l5 ^ (row & 31)) << 2);
                jb[i] = j << 10;
            }
        }

        // fragment bases (A rows 0-48 at rows 0-48; B rows at 49-97)
        const int wr = wv >> 2, wc = wv & 3;
        int ar0 = wr * 32 + fr;                       // <= 47
        int ar1 = ar0 + 16; if (ar1 > 48) ar1 = 48;   // clamp pad rows
        int bc  = wc * 16 + fr; if (bc > 48) bc = 48;
        const int brow = 49 + bc;
        const int aw0 = ar0 << 9, pa0 = ar0 & 31;
        const int aw1 = ar1 << 9, pa1 = ar1 & 31;
        const int bw  = brow << 9, pb = brow & 31;

        f32x4 acc00 = {0.f,0.f,0.f,0.f}, acc10 = {0.f,0.f,0.f,0.f};
        f32x4 aa0 = {0.f,0.f,0.f,0.f}, aa1 = {0.f,0.f,0.f,0.f}, bb = {0.f,0.f,0.f,0.f};

#define L1_ISSUE(DST, s) do {                                                  \
    _Pragma("unroll") for (int i = 0; i < 7; ++i)                              \
        if (jb[i] >= 0) gload16(gp[i] + (size_t)(s) * 128, (DST) + jb[i]);     \
    } while (0)

        // prologue: stage 0 -> buf0
        L1_ISSUE(buf0, 0);
        __syncthreads();

        int p = 0;
#pragma unroll 1
        for (int s = 0; s < 32; ++s) {
            unsigned char* cur = p ? buf1 : buf0;
            unsigned char* nxt = p ? buf0 : buf1;
            if (s < 31) {
                L1_ISSUE(nxt, s + 1);                 // prefetch in flight
                __builtin_amdgcn_sched_barrier(0);    // keep issue above compute
            }
#pragma unroll
            for (int kk = 0; kk < 4; ++kk) {
                const int s0 = kk * 8 + kg * 2;
                bf16x8 a0 = cvt8(ld4(cur + aw0 + (((s0)     ^ pa0) << 4)),
                                 ld4(cur + aw0 + (((s0 + 1) ^ pa0) << 4)));
                bf16x8 a1 = cvt8(ld4(cur + aw1 + (((s0)     ^ pa1) << 4)),
                                 ld4(cur + aw1 + (((s0 + 1) ^ pa1) << 4)));
                bf16x8 b0 = cvt8(ld4(cur + bw  + (((s0)     ^ pb ) << 4)),
                                 ld4(cur + bw  + (((s0 + 1) ^ pb ) << 4)));
                acc00 = __builtin_amdgcn_mfma_f32_16x16x32_bf16(a0, b0, acc00, 0, 0, 0);
                acc10 = __builtin_amdgcn_mfma_f32_16x16x32_bf16(a1, b0, acc10, 0, 0, 0);
                aa0   = __builtin_amdgcn_mfma_f32_16x16x32_bf16(a0, a0, aa0,   0, 0, 0);
                aa1   = __builtin_amdgcn_mfma_f32_16x16x32_bf16(a1, a1, aa1,   0, 0, 0);
                bb    = __builtin_amdgcn_mfma_f32_16x16x32_bf16(b0, b0, bb,    0, 0, 0);
            }
            __syncthreads();   // drains: prefetch arrived + reads of cur done
            p ^= 1;
        }
#undef L1_ISSUE

        // epilogue: disjoint stores (RED) / atomics (fallback)
        float* gout = l1part + (size_t)(RED ? blockIdx.x : batch) * SLOT;
        const int gc = wc * 16 + fr;
#pragma unroll
        for (int rr = 0; rr < 4; ++rr) {
            int gr0 = wr * 32 + kg * 4 + rr;
            int gr1 = gr0 + 16;
            if (gc < HW) {
                if (gr0 < HW) {
                    if (RED) gout[gr0 * HW + gc] = acc00[rr];
                    else atomicAdd(&gout[gr0 * HW + gc], acc00[rr]);
                }
                if (gr1 < HW) {
                    if (RED) gout[gr1 * HW + gc] = acc10[rr];
                    else atomicAdd(&gout[gr1 * HW + gc], acc10[rr]);
                }
            }
        }
        // norms from Gram diagonals: C/D layout col=fr, row=kg*4+rr -> diag
        // element i lives in lane (fr==i, kg==i>>2) at reg rr==i&3.
        if (wc == 0) {
#pragma unroll
            for (int rr = 0; rr < 4; ++rr) {
                int i = kg * 4 + rr;
                if (i == fr) {
                    int r0 = wr * 32 + i;          // 0..47
                    if (RED) gout[PAIRS + r0] = aa0[rr];
                    else atomicAdd(&gout[PAIRS + r0], aa0[rr]);
                    int r1 = r0 + 16;              // wr=1: guard 48
                    if (r1 < HW) {
                        if (RED) gout[PAIRS + r1] = aa1[rr];
                        else atomicAdd(&gout[PAIRS + r1], aa1[rr]);
                    }
                }
            }
        }
        if (wr == 0) {
#pragma unroll
            for (int rr = 0; rr < 4; ++rr) {
                int i = kg * 4 + rr;
                if (i == fr) {
                    int rb_ = wc * 16 + i;
                    if (rb_ < HW) {
                        if (RED) gout[PAIRS + HW + rb_] = bb[rr];
                        else atomicAdd(&gout[PAIRS + HW + rb_], bb[rr]);
                    }
                }
            }
        }
    } else {
        // ================= GK2 role (both tensors + col stats + MSE) =========
        const int chunk = blockIdx.x - 256;
        float* sxA = (float*)shm;                 // 128*68
        float* sxB = sxA + 128 * 68;
        float* scr = sxB + 128 * 68;              // 2048-float scratch
        const int ty = tid >> 5, tx = tid & 31;
        const int q = tid >> 6, cc = tid & 63;

        float accA[8][4], accB[8][4];
#pragma unroll
        for (int r = 0; r < 8; ++r)
#pragma unroll
            for (int c = 0; c < 4; ++c) { accA[r][c] = 0.f; accB[r][c] = 0.f; }
        float cSA[2] = {0.f,0.f}, cQA[2] = {0.f,0.f};
        float cSB[2] = {0.f,0.f}, cQB[2] = {0.f,0.f};
        float mse = 0.f;

#pragma unroll
        for (int st = 0; st < 2; ++st) {
            __syncthreads();
            for (int f = tid; f < 2048; f += 512) {
                int row = f >> 4, c4 = f & 15;
                const float4 a4 = *(const float4*)(z_a + (size_t)row * DIM + chunk * 128 + st * 64 + c4 * 4);
                const float4 b4 = *(const float4*)(z_b + (size_t)row * DIM + chunk * 128 + st * 64 + c4 * 4);
                *(float4*)(sxA + row * 68 + c4 * 4) = a4;
                *(float4*)(sxB + row * 68 + c4 * 4) = b4;
                float dx = a4.x - b4.x, dy = a4.y - b4.y, dz = a4.z - b4.z, dw = a4.w - b4.w;
                mse += dx * dx + dy * dy + dz * dz + dw * dw;
            }
            __syncthreads();
            for (int r = 0; r < 16; ++r) {
                float vA = sxA[(q * 16 + r) * 68 + cc];
                float vB = sxB[(q * 16 + r) * 68 + cc];
                cSA[st] += vA; cQA[st] += vA * vA;
                cSB[st] += vB; cQB[st] += vB * vB;
            }
            for (int k = 0; k < 64; k += 4) {
                float4 ar4[8], br4[8];
#pragma unroll
                for (int r = 0; r < 8; ++r) {
                    ar4[r] = *(const float4*)(sxA + (ty + 16 * r) * 68 + k);
                    br4[r] = *(const float4*)(sxB + (ty + 16 * r) * 68 + k);
                }
#pragma unroll
                for (int c = 0; c < 4; ++c) {
                    float4 ac4 = *(const float4*)(sxA + (tx + 32 * c) * 68 + k);
                    float4 bc4 = *(const float4*)(sxB + (tx + 32 * c) * 68 + k);
#pragma unroll
                    for (int r = 0; r < 8; ++r) {
                        accA[r][c] += ar4[r].x * ac4.x + ar4[r].y * ac4.y + ar4[r].z * ac4.z + ar4[r].w * ac4.w;
                        accB[r][c] += br4[r].x * bc4.x + br4[r].y * bc4.y + br4[r].z * bc4.z + br4[r].w * bc4.w;
                    }
                }
            }
        }
        // column stats: two reduce rounds (A then B) via scratch
#pragma unroll
        for (int tens = 0; tens < 2; ++tens) {
            __syncthreads();
            scr[q * 64 + cc]        = tens ? cSB[0] : cSA[0];
            scr[512 + q * 64 + cc]  = tens ? cSB[1] : cSA[1];
            scr[1024 + q * 64 + cc] = tens ? cQB[0] : cQA[0];
            scr[1536 + q * 64 + cc] = tens ? cQB[1] : cQA[1];
            __syncthreads();
            if (tid < 128) {
                int st = tid >> 6, c2 = tid & 63;
                float s = 0.f, qq = 0.f;
#pragma unroll
                for (int g = 0; g < 8; ++g) {
                    s  += scr[st * 512 + g * 64 + c2];
                    qq += scr[1024 + st * 512 + g * 64 + c2];
                }
                int col = chunk * 128 + st * 64 + c2;
                float* C = ws + COLS_OFF + tens * 2 * DIM;
                C[col] = s; C[DIM + col] = qq;
            }
        }
        // MSE: per-wave reduce + atomic
        for (int o = 32; o; o >>= 1) mse += __shfl_xor(mse, o);
        if ((tid & 63) == 0) atomicAdd(&ws[WS_MSE], mse);
        // Gram out
        if (RED) {
            float* P = ws + GK2PART_OFF + (size_t)chunk * 32768;
#pragma unroll
            for (int r = 0; r < 8; ++r)
#pragma unroll
                for (int c = 0; c < 4; ++c) {
                    P[(ty + 16 * r) * 128 + tx + 32 * c] = accA[r][c];
                    P[16384 + (ty + 16 * r) * 128 + tx + 32 * c] = accB[r][c];
                }
        } else {
#pragma unroll
            for (int r = 0; r < 8; ++r)
#pragma unroll
                for (int c = 0; c < 4; ++c) {
                    atomicAdd(&ws[GRAMA_OFF + (ty + 16 * r) * 128 + tx + 32 * c], accA[r][c]);
                    atomicAdd(&ws[GRAMB_OFF + (ty + 16 * r) * 128 + tx + 32 * c], accB[r][c]);
                }
        }
    }
}

// ---------------------------------------------------------------------------
// MERGE2: blocks 0-127 gk2_reduce; 128-159 gk1b; 160-287 l2_match.
// All roles depend only on uber outputs — no intra-kernel ordering needed.
// ---------------------------------------------------------------------------
template<bool RED>
__global__ __launch_bounds__(256) void merge2(const float* __restrict__ ga,
                                              const float* __restrict__ gb,
                                              float* __restrict__ ws,
                                              const float* __restrict__ l1part)
{
    __shared__ float d2f[PAIRS];
    __shared__ float d2g[PAIRS];
    __shared__ float nAs[49], nBs[49];
    __shared__ float gax[49], gay[49], gbx[49], gby[49];
    __shared__ float mval[4][49];
    __shared__ int   midx[4][49];

    const int b = blockIdx.x;
    const int tid = threadIdx.x;

    if (b < 128) {
        if (!RED) return;        // fallback: Gram accumulated atomically already
        int gid = b * 256 + tid;                 // 0..32767
        int tensor = gid >> 14, e = gid & 16383;
        const float* P = ws + GK2PART_OFF + (size_t)tensor * 16384;
        float s = 0.f;
        for (int c = 0; c < 64; ++c) s += P[(size_t)c * 32768 + e];
        ws[(tensor ? GRAMB_OFF : GRAMA_OFF) + e] = s;
        return;
    }
    if (b < 160) {
        // gk1b: per-column std/relu/diag -> scalars
        int col = (b - 128) * 256 + tid;
        float sa = ws[COLS_OFF + col];
        float qa = ws[COLS_OFF + DIM + col];
        float sb = ws[COLS_OFF + 2 * DIM + col];
        float qb = ws[COLS_OFF + 3 * DIM + col];
        float sA = qa - sa * sa * (1.0f / BATCH);
        float sB = qb - sb * sb * (1.0f / BATCH);
        float rA = fmaxf(0.f, 1.f - sqrtf(sA * (1.0f / (BATCH - 1)) + 1e-4f));
        float rB = fmaxf(0.f, 1.f - sqrtf(sB * (1.0f / (BATCH - 1)) + 1e-4f));
        float dA = sA * sA, dB = sB * sB;
        for (int o = 32; o; o >>= 1) {
            rA += __shfl_xor(rA, o);
            rB += __shfl_xor(rB, o);
            dA += __shfl_xor(dA, o);
            dB += __shfl_xor(dB, o);
        }
        if ((tid & 63) == 0) {
            atomicAdd(&ws[WS_VARA],  rA);
            atomicAdd(&ws[WS_VARB],  rB);
            atomicAdd(&ws[WS_DIAGA], dA);
            atomicAdd(&ws[WS_DIAGB], dB);
        }
        return;
    }

    // l2_match role
    const int batch = b - 160;
    const float* P0 = l1part + (size_t)batch * (RED ? (2 * SLOT) : SLOT);
    auto rd = [&](int off) -> float {
        if (!RED) return P0[off];
        return P0[off] + P0[SLOT + off];
    };

    if (tid < 49) nAs[tid] = rd(PAIRS + tid);
    else if (tid >= 64 && tid < 113) nBs[tid - 64] = rd(PAIRS + 49 + (tid - 64));
    if (tid >= 128 && tid < 177) {
        int i = tid - 128;
        gax[i] = ga[batch * 98 + i * 2];
        gay[i] = ga[batch * 98 + i * 2 + 1];
    } else if (tid >= 192 && tid < 241) {
        int i = tid - 192;
        gbx[i] = gb[batch * 98 + i * 2];
        gby[i] = gb[batch * 98 + i * 2 + 1];
    }
    __syncthreads();
    for (int e = tid; e < PAIRS; e += 256) {
        int i = e / 49, j = e - i * 49;
        d2f[e] = nAs[i] + nBs[j] - 2.0f * rd(e);
        float dx = gax[i] - gbx[j], dy = gay[i] - gby[j];
        d2g[e] = dx * dx + dy * dy;
    }
    __syncthreads();
    const int task = tid >> 6, l = tid & 63;
    if (l < 49) {
        float bv = 3.0e38f; int bi = 0;
        if (task == 0) {
            for (int j = 0; j < 49; ++j) { float v = d2f[l * 49 + j]; if (v < bv) { bv = v; bi = j; } }
        } else if (task == 1) {
            for (int i = 0; i < 49; ++i) { float v = d2f[i * 49 + l]; if (v < bv) { bv = v; bi = i; } }
        } else if (task == 2) {
            for (int j = 0; j < 49; ++j) { float v = d2g[l * 49 + j]; if (v < bv) { bv = v; bi = j; } }
        } else {
            for (int i = 0; i < 49; ++i) { float v = d2g[i * 49 + l]; if (v < bv) { bv = v; bi = i; } }
        }
        mval[task][l] = bv; midx[task][l] = bi;
    }
    __syncthreads();
    if (l < 49) {
        float v = mval[task][l];
        int rank = 0;
        for (int k = 0; k < 49; ++k) {
            float u = mval[task][k];
            rank += (u < v) || (u == v && k < l);   // stable: matches lax.top_k ties
        }
        if (task == 0)      { if (rank < 20) atomicAdd(&ws[WS_S1], v); }
        else if (task == 1) { if (rank < 20) atomicAdd(&ws[WS_S2], v); }
        else if (task == 2) { if (rank < 20) atomicAdd(&ws[WS_S3], d2f[l * 49 + midx[2][l]]); }
        else                { if (rank < 4)  atomicAdd(&ws[WS_S4], d2f[midx[3][l] * 49 + l]); }
    }
}

// ---------------------------------------------------------------------------
// GK3: ||K||_F^2 from the Gram. K = G - (r_i+r_j)/n + S/n^2.
// ---------------------------------------------------------------------------
__global__ __launch_bounds__(256) void gk3_cov(float* __restrict__ ws)
{
    __shared__ float r[128];
    __shared__ float sS;
    __shared__ float wrd[4];
    const int tid = threadIdx.x;
    const float* G = ws + (blockIdx.x ? GRAMB_OFF : GRAMA_OFF);
    if (tid < 128) {
        float s0 = 0.f, s1 = 0.f, s2 = 0.f, s3 = 0.f;
        for (int k = 0; k < 128; k += 4) {
            s0 += G[(k + 0) * 128 + tid];
            s1 += G[(k + 1) * 128 + tid];
            s2 += G[(k + 2) * 128 + tid];
            s3 += G[(k + 3) * 128 + tid];
        }
        r[tid] = (s0 + s1) + (s2 + s3);
    }
    __syncthreads();
    if (tid < 64) {
        float t = r[tid] + r[tid + 64];
        for (int o = 32; o; o >>= 1) t += __shfl_xor(t, o);
        if (tid == 0) sS = t;
    }
    __syncthreads();
    const float S = sS;
    float sk = 0.f;
    for (int e = tid; e < 16384; e += 256) {
        float K = G[e] - (r[e >> 7] + r[e & 127]) * (1.0f / 128.0f) + S * (1.0f / 16384.0f);
        sk += K * K;
    }
    for (int o = 32; o; o >>= 1) sk += __shfl_xor(sk, o);
    if ((tid & 63) == 0) wrd[tid >> 6] = sk;
    __syncthreads();
    if (tid == 0)
        ws[blockIdx.x ? WS_SK2B : WS_SK2A] = wrd[0] + wrd[1] + wrd[2] + wrd[3];
}

// ---------------------------------------------------------------------------
// GK4: final scalar assembly.
// ---------------------------------------------------------------------------
__global__ void gk4_final(const float* __restrict__ ws, float* __restrict__ out)
{
    if (threadIdx.x == 0) {
        float inv_g = ws[WS_MSE] * (1.0f / ((float)BATCH * (float)DIM));
        float varl  = 0.5f * (ws[WS_VARA] + ws[WS_VARB]) * (1.0f / (float)DIM);
        float cov   = (ws[WS_SK2A] - ws[WS_DIAGA] + ws[WS_SK2B] - ws[WS_DIAGB])
                      * (1.0f / (127.0f * 127.0f * (float)DIM));
        float gl = 25.0f * inv_g + 25.0f * varl + cov;
        float m20 = (float)BATCH * 20.0f * (float)DIM;
        float m4  = (float)BATCH * 4.0f  * (float)DIM;
        float invl = 0.5f * (ws[WS_S1] + ws[WS_S2] + ws[WS_S3]) / m20
                   + 0.5f * ws[WS_S4] / m4;
        out[0] = 0.25f * gl + 0.75f * (25.0f * invl);
    }
}

extern "C" void kernel_launch(void* const* d_in, const int* in_sizes, int n_in,
                              void* d_out, int out_size, void* d_ws, size_t ws_size,
                              hipStream_t stream)
{
    (void)in_sizes; (void)n_in; (void)out_size;
    const float* z_a = (const float*)d_in[0];
    const float* z_b = (const float*)d_in[1];
    const float* zla = (const float*)d_in[2];
    const float* zlb = (const float*)d_in[3];
    const float* ga  = (const float*)d_in[4];
    const float* gb  = (const float*)d_in[5];
    float* ws  = (float*)d_ws;
    float* out = (float*)d_out;

    const bool big = ws_size >= (size_t)WS_NEED_FLOATS * sizeof(float);

    if (big) {
        hipMemsetAsync(d_ws, 0, 16 * sizeof(float), stream);
        uber<true><<<320, 512, 0, stream>>>(zla, zlb, z_a, z_b, ws, ws + L1PART_BIG);
        merge2<true><<<288, 256, 0, stream>>>(ga, gb, ws, ws + L1PART_BIG);
        gk3_cov<<<2, 256, 0, stream>>>(ws);
        gk4_final<<<1, 64, 0, stream>>>(ws, out);
    } else {
        hipMemsetAsync(d_ws, 0, (size_t)(L1PART_SMALL + BATCH * SLOT) * sizeof(float), stream);
        uber<false><<<320, 512, 0, stream>>>(zla, zlb, z_a, z_b, ws, ws + L1PART_SMALL);
        merge2<false><<<288, 256, 0, stream>>>(ga, gb, ws, ws + L1PART_SMALL);
        gk3_cov<<<2, 256, 0, stream>>>(ws);
        gk4_final<<<1, 64, 0, stream>>>(ws, out);
    }
}

// Round 10
// 130.996 us; speedup vs baseline: 1.8609x; 1.0920x over previous
//
#include <hip/hip_runtime.h>
#include <math.h>

#define BATCH 128
#define DIM   8192
#define HW    49
#define PAIRS 2401            // 49*49
#define SLOT  2512            // per-partial slot: 2401 G + 49 nA + 49 nB + pad

// ws float offsets
#define WS_MSE    0
#define WS_VARA   1
#define WS_VARB   2
#define WS_DIAGA  3
#define WS_DIAGB  4
#define WS_S1     5
#define WS_S2     6
#define WS_S3     7
#define WS_S4     8
#define WS_SK2A   9
#define WS_SK2B   10
#define COLS_OFF    16                         // saA,qaA,sbB,qbB: 4*DIM
#define GRAMA_OFF   32784
#define GRAMB_OFF   49168
#define GK2PART_OFF 65552                      // 64 chunks * 32768 (A then B)
#define L1PART_BIG  2162704                    // 256 slots * SLOT
#define WS_NEED_FLOATS (L1PART_BIG + 256 * SLOT)    // ~11.2 MB
#define L1PART_SMALL 65552                     // fallback: 128 batch slots (atomic)

typedef __attribute__((ext_vector_type(8))) short bf16x8;
typedef __attribute__((ext_vector_type(4))) float f32x4;

__device__ __forceinline__ unsigned cvtpk(float lo, float hi) {
    unsigned r;
    asm("v_cvt_pk_bf16_f32 %0, %1, %2" : "=v"(r) : "v"(lo), "v"(hi));
    return r;
}
__device__ __forceinline__ bf16x8 cvt8(f32x4 a, f32x4 b) {
    union { unsigned u[4]; bf16x8 v; } r;
    r.u[0] = cvtpk(a.x, a.y); r.u[1] = cvtpk(a.z, a.w);
    r.u[2] = cvtpk(b.x, b.y); r.u[3] = cvtpk(b.z, b.w);
    return r.v;
}
__device__ __forceinline__ f32x4 ld4(const unsigned char* p) {
    return *(const f32x4*)p;
}
// DMA global->LDS, 16B/lane, lane i -> ldsbase + i*16. No VGPR dest => cannot
// be sunk/serialized by the register allocator.
__device__ __forceinline__ void gload16(const float* g, unsigned char* l) {
    __builtin_amdgcn_global_load_lds(
        (const __attribute__((address_space(1))) void*)g,
        (__attribute__((address_space(3))) void*)l, 16, 0, 0);
}

// ---------------------------------------------------------------------------
// UBER kernel, 512 threads, 320 blocks:
//  blocks 0..63   : GK2 role (FIRST in grid so they don't trail the l1 wave) —
//    128x128 Grams of BOTH z_a,z_b (128-col chunk), col sum/sumsq, global MSE.
//  blocks 64..319 : L1 role — per-batch padded 64x64 Gram of 49x8192 features
//    via bf16 MFMA. 128 batches x 2 K-halves (K=4096, 32 stages of BK=128).
//    3-buffer (150KB LDS), 2-deep pipeline with COUNTED per-wave vmcnt + raw
//    s_barrier — outstanding DMA never drains to 0 (T4):
//      iter s: {vmcnt(c) [stage s resident; stage s+1 stays airborne] ->
//               s_barrier -> issue DMA(s+2)->buf[(s+2)%3] -> compute buf[s%3]}
//    Wave 0 issues 7 DMAs/stage, waves 1-7 issue 6 -> per-wave immediates.
//    Row norms from MFMA diagonals (mfma(a,a), mfma(b,b)). Global source 16B
//    slots XOR-permuted (slot ^ (row&31), involution) for low-conflict
//    fragment ds_read_b128; DMA LDS dest linear (1 instr = 2 rows x 512B).
// ---------------------------------------------------------------------------
template<bool RED>
__global__ __launch_bounds__(512) void uber(const float* __restrict__ za_l,
                                            const float* __restrict__ zb_l,
                                            const float* __restrict__ z_a,
                                            const float* __restrict__ z_b,
                                            float* __restrict__ ws,
                                            float* __restrict__ l1part)
{
    __shared__ __align__(16) unsigned char shm[150528];
    const int tid = threadIdx.x;

    if (blockIdx.x >= 64) {
        // ================= L1 role =================
        const int lb = blockIdx.x - 64;            // 0..255
        unsigned char* buf0 = shm;
        unsigned char* buf1 = shm + 50176;
        unsigned char* buf2 = shm + 100352;
        const int wv = tid >> 6, lane = tid & 63;
        const int fr = lane & 15, kg = lane >> 4;
        const int batch = lb >> 1;
        const int kh    = lb & 1;
        const float* Az = za_l + (size_t)batch * HW * DIM + (size_t)kh * 4096;
        const float* Bz = zb_l + (size_t)batch * HW * DIM + (size_t)kh * 4096;

        // DMA descriptors: pair j = wv + 8i covers rows 2j (lanes 0-31) and
        // 2j+1 (lanes 32-63); LDS dest linear at j*1024 + lane*16.
        const float* gp[7];
        int jb[7];
        const int half = lane >> 5, l5 = lane & 31;
#pragma unroll
        for (int i = 0; i < 7; ++i) {
            int j = wv + 8 * i;
            gp[i] = Az; jb[i] = -1;
            if (j < 49) {
                int row = 2 * j + half;
                const float* rbase = (row < 49) ? (Az + (size_t)row * DIM)
                                                : (Bz + (size_t)(row - 49) * DIM);
                gp[i] = rbase + ((l5 ^ (row & 31)) << 2);
                jb[i] = j << 10;
            }
        }

        // fragment bases (A rows 0-48; B rows 49-97)
        const int wr = wv >> 2, wc = wv & 3;
        int ar0 = wr * 32 + fr;                       // <= 47
        int ar1 = ar0 + 16; if (ar1 > 48) ar1 = 48;   // clamp pad rows
        int bc  = wc * 16 + fr; if (bc > 48) bc = 48;
        const int brow = 49 + bc;
        const int aw0 = ar0 << 9, pa0 = ar0 & 31;
        const int aw1 = ar1 << 9, pa1 = ar1 & 31;
        const int bw  = brow << 9, pb = brow & 31;

        f32x4 acc00 = {0.f,0.f,0.f,0.f}, acc10 = {0.f,0.f,0.f,0.f};
        f32x4 aa0 = {0.f,0.f,0.f,0.f}, aa1 = {0.f,0.f,0.f,0.f}, bb = {0.f,0.f,0.f,0.f};

#define L1_ISSUE(DST, s) do {                                                  \
    _Pragma("unroll") for (int i = 0; i < 7; ++i)                              \
        if (jb[i] >= 0) gload16(gp[i] + (size_t)(s) * 128, (DST) + jb[i]);     \
    } while (0)

        // prologue: stages 0,1 airborne (per-wave outstanding = 2c)
        L1_ISSUE(buf0, 0);
        L1_ISSUE(buf1, 1);

        int m = 0;    // s % 3
#pragma unroll 1
        for (int s = 0; s < 32; ++s) {
            // wait until stage s resident; stage s+1 (newest c) stays in flight
            if (s == 31)      asm volatile("s_waitcnt vmcnt(0)" ::: "memory");
            else if (wv == 0) asm volatile("s_waitcnt vmcnt(7)" ::: "memory");
            else              asm volatile("s_waitcnt vmcnt(6)" ::: "memory");
            __builtin_amdgcn_sched_barrier(0);
            __builtin_amdgcn_s_barrier();      // all waves: stage s resident;
            __builtin_amdgcn_sched_barrier(0); // all compute(s-1) complete
            if (s <= 29) {
                int m2 = m + 2; if (m2 >= 3) m2 -= 3;
                unsigned char* nxt = (m2 == 0) ? buf0 : (m2 == 1) ? buf1 : buf2;
                L1_ISSUE(nxt, s + 2);          // overwrites buf of stage s-1: safe
                __builtin_amdgcn_sched_barrier(0);
            }
            unsigned char* cur = (m == 0) ? buf0 : (m == 1) ? buf1 : buf2;
#pragma unroll
            for (int kk = 0; kk < 4; ++kk) {
                const int s0 = kk * 8 + kg * 2;
                bf16x8 a0 = cvt8(ld4(cur + aw0 + (((s0)     ^ pa0) << 4)),
                                 ld4(cur + aw0 + (((s0 + 1) ^ pa0) << 4)));
                bf16x8 a1 = cvt8(ld4(cur + aw1 + (((s0)     ^ pa1) << 4)),
                                 ld4(cur + aw1 + (((s0 + 1) ^ pa1) << 4)));
                bf16x8 b0 = cvt8(ld4(cur + bw  + (((s0)     ^ pb ) << 4)),
                                 ld4(cur + bw  + (((s0 + 1) ^ pb ) << 4)));
                acc00 = __builtin_amdgcn_mfma_f32_16x16x32_bf16(a0, b0, acc00, 0, 0, 0);
                acc10 = __builtin_amdgcn_mfma_f32_16x16x32_bf16(a1, b0, acc10, 0, 0, 0);
                aa0   = __builtin_amdgcn_mfma_f32_16x16x32_bf16(a0, a0, aa0,   0, 0, 0);
                aa1   = __builtin_amdgcn_mfma_f32_16x16x32_bf16(a1, a1, aa1,   0, 0, 0);
                bb    = __builtin_amdgcn_mfma_f32_16x16x32_bf16(b0, b0, bb,    0, 0, 0);
            }
            m = (m == 2) ? 0 : m + 1;
        }
#undef L1_ISSUE

        // epilogue: disjoint stores (RED) / atomics (fallback)
        float* gout = l1part + (size_t)(RED ? lb : batch) * SLOT;
        const int gc = wc * 16 + fr;
#pragma unroll
        for (int rr = 0; rr < 4; ++rr) {
            int gr0 = wr * 32 + kg * 4 + rr;
            int gr1 = gr0 + 16;
            if (gc < HW) {
                if (gr0 < HW) {
                    if (RED) gout[gr0 * HW + gc] = acc00[rr];
                    else atomicAdd(&gout[gr0 * HW + gc], acc00[rr]);
                }
                if (gr1 < HW) {
                    if (RED) gout[gr1 * HW + gc] = acc10[rr];
                    else atomicAdd(&gout[gr1 * HW + gc], acc10[rr]);
                }
            }
        }
        // norms from Gram diagonals: C/D col=fr, row=kg*4+rr -> diag at fr==i
        if (wc == 0) {
#pragma unroll
            for (int rr = 0; rr < 4; ++rr) {
                int i = kg * 4 + rr;
                if (i == fr) {
                    int r0 = wr * 32 + i;
                    if (RED) gout[PAIRS + r0] = aa0[rr];
                    else atomicAdd(&gout[PAIRS + r0], aa0[rr]);
                    int r1 = r0 + 16;
                    if (r1 < HW) {
                        if (RED) gout[PAIRS + r1] = aa1[rr];
                        else atomicAdd(&gout[PAIRS + r1], aa1[rr]);
                    }
                }
            }
        }
        if (wr == 0) {
#pragma unroll
            for (int rr = 0; rr < 4; ++rr) {
                int i = kg * 4 + rr;
                if (i == fr) {
                    int rb_ = wc * 16 + i;
                    if (rb_ < HW) {
                        if (RED) gout[PAIRS + HW + rb_] = bb[rr];
                        else atomicAdd(&gout[PAIRS + HW + rb_], bb[rr]);
                    }
                }
            }
        }
    } else {
        // ================= GK2 role (both tensors + col stats + MSE) =========
        const int chunk = blockIdx.x;
        float* sxA = (float*)shm;                 // 128*68
        float* sxB = sxA + 128 * 68;
        float* scr = sxB + 128 * 68;              // 2048-float scratch
        const int ty = tid >> 5, tx = tid & 31;
        const int q = tid >> 6, cc = tid & 63;

        float accA[8][4], accB[8][4];
#pragma unroll
        for (int r = 0; r < 8; ++r)
#pragma unroll
            for (int c = 0; c < 4; ++c) { accA[r][c] = 0.f; accB[r][c] = 0.f; }
        float cSA[2] = {0.f,0.f}, cQA[2] = {0.f,0.f};
        float cSB[2] = {0.f,0.f}, cQB[2] = {0.f,0.f};
        float mse = 0.f;

#pragma unroll
        for (int st = 0; st < 2; ++st) {
            __syncthreads();
            for (int f = tid; f < 2048; f += 512) {
                int row = f >> 4, c4 = f & 15;
                const float4 a4 = *(const float4*)(z_a + (size_t)row * DIM + chunk * 128 + st * 64 + c4 * 4);
                const float4 b4 = *(const float4*)(z_b + (size_t)row * DIM + chunk * 128 + st * 64 + c4 * 4);
                *(float4*)(sxA + row * 68 + c4 * 4) = a4;
                *(float4*)(sxB + row * 68 + c4 * 4) = b4;
                float dx = a4.x - b4.x, dy = a4.y - b4.y, dz = a4.z - b4.z, dw = a4.w - b4.w;
                mse += dx * dx + dy * dy + dz * dz + dw * dw;
            }
            __syncthreads();
            for (int r = 0; r < 16; ++r) {
                float vA = sxA[(q * 16 + r) * 68 + cc];
                float vB = sxB[(q * 16 + r) * 68 + cc];
                cSA[st] += vA; cQA[st] += vA * vA;
                cSB[st] += vB; cQB[st] += vB * vB;
            }
            for (int k = 0; k < 64; k += 4) {
                float4 ar4[8], br4[8];
#pragma unroll
                for (int r = 0; r < 8; ++r) {
                    ar4[r] = *(const float4*)(sxA + (ty + 16 * r) * 68 + k);
                    br4[r] = *(const float4*)(sxB + (ty + 16 * r) * 68 + k);
                }
#pragma unroll
                for (int c = 0; c < 4; ++c) {
                    float4 ac4 = *(const float4*)(sxA + (tx + 32 * c) * 68 + k);
                    float4 bc4 = *(const float4*)(sxB + (tx + 32 * c) * 68 + k);
#pragma unroll
                    for (int r = 0; r < 8; ++r) {
                        accA[r][c] += ar4[r].x * ac4.x + ar4[r].y * ac4.y + ar4[r].z * ac4.z + ar4[r].w * ac4.w;
                        accB[r][c] += br4[r].x * bc4.x + br4[r].y * bc4.y + br4[r].z * bc4.z + br4[r].w * bc4.w;
                    }
                }
            }
        }
        // column stats: two reduce rounds (A then B) via scratch
#pragma unroll
        for (int tens = 0; tens < 2; ++tens) {
            __syncthreads();
            scr[q * 64 + cc]        = tens ? cSB[0] : cSA[0];
            scr[512 + q * 64 + cc]  = tens ? cSB[1] : cSA[1];
            scr[1024 + q * 64 + cc] = tens ? cQB[0] : cQA[0];
            scr[1536 + q * 64 + cc] = tens ? cQB[1] : cQA[1];
            __syncthreads();
            if (tid < 128) {
                int st = tid >> 6, c2 = tid & 63;
                float s = 0.f, qq = 0.f;
#pragma unroll
                for (int g = 0; g < 8; ++g) {
                    s  += scr[st * 512 + g * 64 + c2];
                    qq += scr[1024 + st * 512 + g * 64 + c2];
                }
                int col = chunk * 128 + st * 64 + c2;
                float* C = ws + COLS_OFF + tens * 2 * DIM;
                C[col] = s; C[DIM + col] = qq;
            }
        }
        // MSE: per-wave reduce + atomic
        for (int o = 32; o; o >>= 1) mse += __shfl_xor(mse, o);
        if ((tid & 63) == 0) atomicAdd(&ws[WS_MSE], mse);
        // Gram out
        if (RED) {
            float* P = ws + GK2PART_OFF + (size_t)chunk * 32768;
#pragma unroll
            for (int r = 0; r < 8; ++r)
#pragma unroll
                for (int c = 0; c < 4; ++c) {
                    P[(ty + 16 * r) * 128 + tx + 32 * c] = accA[r][c];
                    P[16384 + (ty + 16 * r) * 128 + tx + 32 * c] = accB[r][c];
                }
        } else {
#pragma unroll
            for (int r = 0; r < 8; ++r)
#pragma unroll
                for (int c = 0; c < 4; ++c) {
                    atomicAdd(&ws[GRAMA_OFF + (ty + 16 * r) * 128 + tx + 32 * c], accA[r][c]);
                    atomicAdd(&ws[GRAMB_OFF + (ty + 16 * r) * 128 + tx + 32 * c], accB[r][c]);
                }
        }
    }
}

// ---------------------------------------------------------------------------
// MERGE2: blocks 0-127 gk2_reduce; 128-159 gk1b; 160-287 l2_match.
// ---------------------------------------------------------------------------
template<bool RED>
__global__ __launch_bounds__(256) void merge2(const float* __restrict__ ga,
                                              const float* __restrict__ gb,
                                              float* __restrict__ ws,
                                              const float* __restrict__ l1part)
{
    __shared__ float d2f[PAIRS];
    __shared__ float d2g[PAIRS];
    __shared__ float nAs[49], nBs[49];
    __shared__ float gax[49], gay[49], gbx[49], gby[49];
    __shared__ float mval[4][49];
    __shared__ int   midx[4][49];

    const int b = blockIdx.x;
    const int tid = threadIdx.x;

    if (b < 128) {
        if (!RED) return;
        int gid = b * 256 + tid;                 // 0..32767
        int tensor = gid >> 14, e = gid & 16383;
        const float* P = ws + GK2PART_OFF + (size_t)tensor * 16384;
        float s = 0.f;
        for (int c = 0; c < 64; ++c) s += P[(size_t)c * 32768 + e];
        ws[(tensor ? GRAMB_OFF : GRAMA_OFF) + e] = s;
        return;
    }
    if (b < 160) {
        int col = (b - 128) * 256 + tid;
        float sa = ws[COLS_OFF + col];
        float qa = ws[COLS_OFF + DIM + col];
        float sb = ws[COLS_OFF + 2 * DIM + col];
        float qb = ws[COLS_OFF + 3 * DIM + col];
        float sA = qa - sa * sa * (1.0f / BATCH);
        float sB = qb - sb * sb * (1.0f / BATCH);
        float rA = fmaxf(0.f, 1.f - sqrtf(sA * (1.0f / (BATCH - 1)) + 1e-4f));
        float rB = fmaxf(0.f, 1.f - sqrtf(sB * (1.0f / (BATCH - 1)) + 1e-4f));
        float dA = sA * sA, dB = sB * sB;
        for (int o = 32; o; o >>= 1) {
            rA += __shfl_xor(rA, o);
            rB += __shfl_xor(rB, o);
            dA += __shfl_xor(dA, o);
            dB += __shfl_xor(dB, o);
        }
        if ((tid & 63) == 0) {
            atomicAdd(&ws[WS_VARA],  rA);
            atomicAdd(&ws[WS_VARB],  rB);
            atomicAdd(&ws[WS_DIAGA], dA);
            atomicAdd(&ws[WS_DIAGB], dB);
        }
        return;
    }

    // l2_match role
    const int batch = b - 160;
    const float* P0 = l1part + (size_t)batch * (RED ? (2 * SLOT) : SLOT);
    auto rd = [&](int off) -> float {
        if (!RED) return P0[off];
        return P0[off] + P0[SLOT + off];
    };

    if (tid < 49) nAs[tid] = rd(PAIRS + tid);
    else if (tid >= 64 && tid < 113) nBs[tid - 64] = rd(PAIRS + 49 + (tid - 64));
    if (tid >= 128 && tid < 177) {
        int i = tid - 128;
        gax[i] = ga[batch * 98 + i * 2];
        gay[i] = ga[batch * 98 + i * 2 + 1];
    } else if (tid >= 192 && tid < 241) {
        int i = tid - 192;
        gbx[i] = gb[batch * 98 + i * 2];
        gby[i] = gb[batch * 98 + i * 2 + 1];
    }
    __syncthreads();
    for (int e = tid; e < PAIRS; e += 256) {
        int i = e / 49, j = e - i * 49;
        d2f[e] = nAs[i] + nBs[j] - 2.0f * rd(e);
        float dx = gax[i] - gbx[j], dy = gay[i] - gby[j];
        d2g[e] = dx * dx + dy * dy;
    }
    __syncthreads();
    const int task = tid >> 6, l = tid & 63;
    if (l < 49) {
        float bv = 3.0e38f; int bi = 0;
        if (task == 0) {
            for (int j = 0; j < 49; ++j) { float v = d2f[l * 49 + j]; if (v < bv) { bv = v; bi = j; } }
        } else if (task == 1) {
            for (int i = 0; i < 49; ++i) { float v = d2f[i * 49 + l]; if (v < bv) { bv = v; bi = i; } }
        } else if (task == 2) {
            for (int j = 0; j < 49; ++j) { float v = d2g[l * 49 + j]; if (v < bv) { bv = v; bi = j; } }
        } else {
            for (int i = 0; i < 49; ++i) { float v = d2g[i * 49 + l]; if (v < bv) { bv = v; bi = i; } }
        }
        mval[task][l] = bv; midx[task][l] = bi;
    }
    __syncthreads();
    if (l < 49) {
        float v = mval[task][l];
        int rank = 0;
        for (int k = 0; k < 49; ++k) {
            float u = mval[task][k];
            rank += (u < v) || (u == v && k < l);   // stable: matches lax.top_k ties
        }
        if (task == 0)      { if (rank < 20) atomicAdd(&ws[WS_S1], v); }
        else if (task == 1) { if (rank < 20) atomicAdd(&ws[WS_S2], v); }
        else if (task == 2) { if (rank < 20) atomicAdd(&ws[WS_S3], d2f[l * 49 + midx[2][l]]); }
        else                { if (rank < 4)  atomicAdd(&ws[WS_S4], d2f[midx[3][l] * 49 + l]); }
    }
}

// ---------------------------------------------------------------------------
// GK3: ||K||_F^2 from the Gram. K = G - (r_i+r_j)/n + S/n^2.
// ---------------------------------------------------------------------------
__global__ __launch_bounds__(256) void gk3_cov(float* __restrict__ ws)
{
    __shared__ float r[128];
    __shared__ float sS;
    __shared__ float wrd[4];
    const int tid = threadIdx.x;
    const float* G = ws + (blockIdx.x ? GRAMB_OFF : GRAMA_OFF);
    if (tid < 128) {
        float s0 = 0.f, s1 = 0.f, s2 = 0.f, s3 = 0.f;
        for (int k = 0; k < 128; k += 4) {
            s0 += G[(k + 0) * 128 + tid];
            s1 += G[(k + 1) * 128 + tid];
            s2 += G[(k + 2) * 128 + tid];
            s3 += G[(k + 3) * 128 + tid];
        }
        r[tid] = (s0 + s1) + (s2 + s3);
    }
    __syncthreads();
    if (tid < 64) {
        float t = r[tid] + r[tid + 64];
        for (int o = 32; o; o >>= 1) t += __shfl_xor(t, o);
        if (tid == 0) sS = t;
    }
    __syncthreads();
    const float S = sS;
    float sk = 0.f;
    for (int e = tid; e < 16384; e += 256) {
        float K = G[e] - (r[e >> 7] + r[e & 127]) * (1.0f / 128.0f) + S * (1.0f / 16384.0f);
        sk += K * K;
    }
    for (int o = 32; o; o >>= 1) sk += __shfl_xor(sk, o);
    if ((tid & 63) == 0) wrd[tid >> 6] = sk;
    __syncthreads();
    if (tid == 0)
        ws[blockIdx.x ? WS_SK2B : WS_SK2A] = wrd[0] + wrd[1] + wrd[2] + wrd[3];
}

// ---------------------------------------------------------------------------
// GK4: final scalar assembly.
// ---------------------------------------------------------------------------
__global__ void gk4_final(const float* __restrict__ ws, float* __restrict__ out)
{
    if (threadIdx.x == 0) {
        float inv_g = ws[WS_MSE] * (1.0f / ((float)BATCH * (float)DIM));
        float varl  = 0.5f * (ws[WS_VARA] + ws[WS_VARB]) * (1.0f / (float)DIM);
        float cov   = (ws[WS_SK2A] - ws[WS_DIAGA] + ws[WS_SK2B] - ws[WS_DIAGB])
                      * (1.0f / (127.0f * 127.0f * (float)DIM));
        float gl = 25.0f * inv_g + 25.0f * varl + cov;
        float m20 = (float)BATCH * 20.0f * (float)DIM;
        float m4  = (float)BATCH * 4.0f  * (float)DIM;
        float invl = 0.5f * (ws[WS_S1] + ws[WS_S2] + ws[WS_S3]) / m20
                   + 0.5f * ws[WS_S4] / m4;
        out[0] = 0.25f * gl + 0.75f * (25.0f * invl);
    }
}

extern "C" void kernel_launch(void* const* d_in, const int* in_sizes, int n_in,
                              void* d_out, int out_size, void* d_ws, size_t ws_size,
                              hipStream_t stream)
{
    (void)in_sizes; (void)n_in; (void)out_size;
    const float* z_a = (const float*)d_in[0];
    const float* z_b = (const float*)d_in[1];
    const float* zla = (const float*)d_in[2];
    const float* zlb = (const float*)d_in[3];
    const float* ga  = (const float*)d_in[4];
    const float* gb  = (const float*)d_in[5];
    float* ws  = (float*)d_ws;
    float* out = (float*)d_out;

    const bool big = ws_size >= (size_t)WS_NEED_FLOATS * sizeof(float);

    if (big) {
        hipMemsetAsync(d_ws, 0, 16 * sizeof(float), stream);
        uber<true><<<320, 512, 0, stream>>>(zla, zlb, z_a, z_b, ws, ws + L1PART_BIG);
        merge2<true><<<288, 256, 0, stream>>>(ga, gb, ws, ws + L1PART_BIG);
        gk3_cov<<<2, 256, 0, stream>>>(ws);
        gk4_final<<<1, 64, 0, stream>>>(ws, out);
    } else {
        hipMemsetAsync(d_ws, 0, (size_t)(L1PART_SMALL + BATCH * SLOT) * sizeof(float), stream);
        uber<false><<<320, 512, 0, stream>>>(zla, zlb, z_a, z_b, ws, ws + L1PART_SMALL);
        merge2<false><<<288, 256, 0, stream>>>(ga, gb, ws, ws + L1PART_SMALL);
        gk3_cov<<<2, 256, 0, stream>>>(ws);
        gk4_final<<<1, 64, 0, stream>>>(ws, out);
    }
}